// Round 5
// baseline (2239.341 us; speedup 1.0000x reference)
//
#include <hip/hip_runtime.h>
#include <hip/hip_bf16.h>
#include <math.h>

// Problem constants
#define BB 4
#define NN 1024
#define MM 512
#define DD 512
#define PP 256
#define HH 8
#define DHH 64
#define LL 6
#define FFI 2048

typedef unsigned short u16;
typedef __attribute__((ext_vector_type(8))) short frag8;   // 8 bf16 (4 VGPRs)
typedef __attribute__((ext_vector_type(4))) float f32x4;   // MFMA C/D

__device__ __forceinline__ u16 f2bf(float f) {
  union { float f; unsigned u; } x; x.f = f;
  unsigned u = x.u;
  return (u16)((u + 0x7FFFu + ((u >> 16) & 1u)) >> 16);
}

// ---------------------------------------------------------------------------
// LayerNorm: y[row] = LN(x[row]) * g (+ resid[row]); obf => write bf16
// ---------------------------------------------------------------------------
__global__ __launch_bounds__(256) void ln_kernel(const float* __restrict__ x,
                                                 const float* __restrict__ g,
                                                 const float* __restrict__ resid,
                                                 void* __restrict__ y,
                                                 int cols, int stable, int obf) {
  __shared__ float sbuf[8];
  int row = blockIdx.x;
  const float* xr = x + (size_t)row * cols;
  int tid = threadIdx.x;

  float inv_mx = 1.f;
  if (stable) {
    float mx = -INFINITY;
    for (int c = tid; c < cols; c += 256) mx = fmaxf(mx, xr[c]);
    #pragma unroll
    for (int o = 32; o > 0; o >>= 1) mx = fmaxf(mx, __shfl_xor(mx, o));
    if ((tid & 63) == 0) sbuf[tid >> 6] = mx;
    __syncthreads();
    mx = fmaxf(fmaxf(sbuf[0], sbuf[1]), fmaxf(sbuf[2], sbuf[3]));
    __syncthreads();
    inv_mx = 1.f / mx;
  }

  float sum = 0.f, ss = 0.f;
  for (int c = tid; c < cols; c += 256) {
    float v = xr[c] * inv_mx;
    sum += v; ss += v * v;
  }
  #pragma unroll
  for (int o = 32; o > 0; o >>= 1) { sum += __shfl_xor(sum, o); ss += __shfl_xor(ss, o); }
  if ((tid & 63) == 0) { sbuf[tid >> 6] = sum; sbuf[4 + (tid >> 6)] = ss; }
  __syncthreads();
  sum = sbuf[0] + sbuf[1] + sbuf[2] + sbuf[3];
  ss  = sbuf[4] + sbuf[5] + sbuf[6] + sbuf[7];

  float mean = sum / cols;
  float var  = ss / cols - mean * mean;
  float r = rsqrtf(var + 1e-5f);
  for (int c = tid; c < cols; c += 256) {
    float v = (xr[c] * inv_mx - mean) * r * g[c];
    if (resid) v += resid[(size_t)row * cols + c];
    if (obf) ((u16*)y)[(size_t)row * cols + c] = f2bf(v);
    else     ((float*)y)[(size_t)row * cols + c] = v;
  }
}

// ---------------------------------------------------------------------------
// Weight convert + transpose: W (K x N fp32, layer stride K*N) -> Wt (N x K bf16)
// ---------------------------------------------------------------------------
__global__ __launch_bounds__(256) void wtrans_kernel(const float* __restrict__ W,
                                                     u16* __restrict__ Wt,
                                                     int K, int N) {
  __shared__ float tile[32][33];
  size_t lofs = (size_t)blockIdx.z * K * N;
  const float* Wl = W + lofs;
  u16* Wtl = Wt + lofs;
  int n0 = blockIdx.x * 32, k0 = blockIdx.y * 32;
  int t = threadIdx.x;
  #pragma unroll
  for (int it = 0; it < 4; it++) {
    int idx = t + it * 256;
    int r = idx >> 5, c = idx & 31;
    tile[r][c] = Wl[(size_t)(k0 + r) * N + n0 + c];
  }
  __syncthreads();
  #pragma unroll
  for (int it = 0; it < 4; it++) {
    int idx = t + it * 256;
    int r = idx >> 5, c = idx & 31;
    Wtl[(size_t)(n0 + r) * K + k0 + c] = f2bf(tile[c][r]);
  }
}

// ---------------------------------------------------------------------------
// bf16 MFMA GEMM: C(MxN) = A(MxK,bf16) @ Bt(NxK,bf16)^T  [+ res fp32]
// QEPI=1: instead of writing C fp32, write q bf16 (B,H,N,64) with *0.125
//         scale and optional rotary (requires TN=128; rotary pairs are
//         lane-local across the j=0/j=1 accumulator registers).
// ---------------------------------------------------------------------------
#define LSTR 40

template<int TM, int TN, int RES, int QEPI>
__global__ __launch_bounds__(256) void mfma_gemm(const u16* __restrict__ A,
                                                 const u16* __restrict__ Bt,
                                                 float* __restrict__ C,
                                                 const float* __restrict__ res,
                                                 int M, int N, int K,
                                                 u16* __restrict__ qout, int use_rot) {
  constexpr int TM2 = TM / 2, TN2 = TN / 2;
  constexpr int IT = TM2 / 16, JT = TN2 / 16;
  constexpr int ASLOT = TM * 4 / 256, BSLOT = TN * 4 / 256;
  __shared__ u16 As[TM * LSTR];
  __shared__ u16 Bs[TN * LSTR];
  int t = threadIdx.x;
  int w = t >> 6, lane = t & 63;
  int bm = blockIdx.y * TM, bn = blockIdx.x * TN;
  int wr = (w >> 1) * TM2, wc = (w & 1) * TN2;
  int lm = lane & 15, q = lane >> 4;

  f32x4 acc[IT][JT] = {};

  for (int k0 = 0; k0 < K; k0 += 32) {
    __syncthreads();
    #pragma unroll
    for (int i = 0; i < ASLOT; i++) {
      int s = t + i * 256; int m = s >> 2, c = s & 3;
      uint4 d = *(const uint4*)(A + (size_t)(bm + m) * K + k0 + c * 8);
      *(uint4*)&As[m * LSTR + c * 8] = d;
    }
    #pragma unroll
    for (int i = 0; i < BSLOT; i++) {
      int s = t + i * 256; int n = s >> 2, c = s & 3;
      uint4 d = *(const uint4*)(Bt + (size_t)(bn + n) * K + k0 + c * 8);
      *(uint4*)&Bs[n * LSTR + c * 8] = d;
    }
    __syncthreads();
    frag8 a[IT], b[JT];
    #pragma unroll
    for (int i = 0; i < IT; i++) a[i] = *(const frag8*)&As[(wr + i * 16 + lm) * LSTR + q * 8];
    #pragma unroll
    for (int j = 0; j < JT; j++) b[j] = *(const frag8*)&Bs[(wc + j * 16 + lm) * LSTR + q * 8];
    #pragma unroll
    for (int i = 0; i < IT; i++)
      #pragma unroll
      for (int j = 0; j < JT; j++)
        acc[i][j] = __builtin_amdgcn_mfma_f32_16x16x32_bf16(a[i], b[j], acc[i][j], 0, 0, 0);
  }

  if (QEPI) {
    // wave spans exactly one head (64 cols); d = j*16+lm
    int h = (bn + wc) >> 6;
    float invf = __powf(10000.f, -(float)lm * (1.f / 16.f));
    #pragma unroll
    for (int i = 0; i < IT; i++) {
      #pragma unroll
      for (int r = 0; r < 4; r++) {
        int row = bm + wr + i * 16 + q * 4 + r;
        int b2 = row >> 10, n2 = row & 1023;
        float vals[JT];
        #pragma unroll
        for (int j = 0; j < JT; j++) vals[j] = acc[i][j][r] * 0.125f;
        if (use_rot) {
          float a = (float)n2 * invf;
          float s0 = sinf(a), c0 = cosf(a);
          float v0 = vals[0], v1 = vals[1];
          vals[0] = v0 * c0 - v1 * s0;
          vals[1] = v1 * c0 + v0 * s0;
        }
        u16* dst = qout + (((size_t)(b2 * 8 + h) * 1024 + n2) << 6);
        #pragma unroll
        for (int j = 0; j < JT; j++) dst[j * 16 + lm] = f2bf(vals[j]);
      }
    }
  } else {
    #pragma unroll
    for (int i = 0; i < IT; i++)
      #pragma unroll
      for (int j = 0; j < JT; j++)
        #pragma unroll
        for (int r = 0; r < 4; r++) {
          int row = bm + wr + i * 16 + q * 4 + r;
          int col = bn + wc + j * 16 + lm;
          float v = acc[i][j][r];
          if (RES) v += res[(size_t)row * N + col];
          C[(size_t)row * N + col] = v;
        }
  }
}

// ---------------------------------------------------------------------------
// Gated FF MFMA GEMM: Bt is (2*FI) x K; out C(M x FI, bf16) = h * silu(gate)
// ---------------------------------------------------------------------------
__global__ __launch_bounds__(256) void mfma_gemm_gated(const u16* __restrict__ A,
                                                       const u16* __restrict__ Bt,
                                                       u16* __restrict__ C,
                                                       int M, int FI, int K) {
  constexpr int TM = 128, TN = 64;
  constexpr int TM2 = 64, TN2 = 32;
  constexpr int IT = 4, JT = 2;
  __shared__ u16 As[TM * LSTR];
  __shared__ u16 Bh[TN * LSTR];
  __shared__ u16 Bg[TN * LSTR];
  int t = threadIdx.x;
  int w = t >> 6, lane = t & 63;
  int bm = blockIdx.y * TM, bn = blockIdx.x * TN;
  int wr = (w >> 1) * TM2, wc = (w & 1) * TN2;
  int lm = lane & 15, q = lane >> 4;

  f32x4 ah[IT][JT] = {};
  f32x4 ag[IT][JT] = {};

  for (int k0 = 0; k0 < K; k0 += 32) {
    __syncthreads();
    #pragma unroll
    for (int i = 0; i < 2; i++) {
      int s = t + i * 256; int m = s >> 2, c = s & 3;
      uint4 d = *(const uint4*)(A + (size_t)(bm + m) * K + k0 + c * 8);
      *(uint4*)&As[m * LSTR + c * 8] = d;
    }
    {
      int s = t; int n = s >> 2, c = s & 3;
      uint4 dh = *(const uint4*)(Bt + (size_t)(bn + n) * K + k0 + c * 8);
      uint4 dg = *(const uint4*)(Bt + (size_t)(bn + FI + n) * K + k0 + c * 8);
      *(uint4*)&Bh[n * LSTR + c * 8] = dh;
      *(uint4*)&Bg[n * LSTR + c * 8] = dg;
    }
    __syncthreads();
    frag8 a[IT], bh[JT], bg[JT];
    #pragma unroll
    for (int i = 0; i < IT; i++) a[i] = *(const frag8*)&As[(wr + i * 16 + lm) * LSTR + q * 8];
    #pragma unroll
    for (int j = 0; j < JT; j++) {
      bh[j] = *(const frag8*)&Bh[(wc + j * 16 + lm) * LSTR + q * 8];
      bg[j] = *(const frag8*)&Bg[(wc + j * 16 + lm) * LSTR + q * 8];
    }
    #pragma unroll
    for (int i = 0; i < IT; i++)
      #pragma unroll
      for (int j = 0; j < JT; j++) {
        ah[i][j] = __builtin_amdgcn_mfma_f32_16x16x32_bf16(a[i], bh[j], ah[i][j], 0, 0, 0);
        ag[i][j] = __builtin_amdgcn_mfma_f32_16x16x32_bf16(a[i], bg[j], ag[i][j], 0, 0, 0);
      }
  }

  #pragma unroll
  for (int i = 0; i < IT; i++)
    #pragma unroll
    for (int j = 0; j < JT; j++)
      #pragma unroll
      for (int r = 0; r < 4; r++) {
        int row = bm + wr + i * 16 + q * 4 + r;
        int col = bn + wc + j * 16 + lm;
        float h = ah[i][j][r], g = ag[i][j][r];
        float sg = 1.f / (1.f + __expf(-g));
        C[(size_t)row * FI + col] = f2bf(h * g * sg);
      }
}

// ---------------------------------------------------------------------------
// Bias table: tab[h][delta] = rel_emb[bucket(delta)][h], delta in [0,1024)
// ---------------------------------------------------------------------------
__global__ __launch_bounds__(256) void biasprep_kernel(const float* __restrict__ rel_emb,
                                                       float* __restrict__ tab) {
  int idx = blockIdx.x * 256 + threadIdx.x;   // 8192
  int h = idx >> 10, delta = idx & 1023;
  int bucket;
  if (delta < 16) bucket = delta;
  else {
    bucket = 16 + (int)(__logf((float)delta * (1.f / 16.f)) * (16.f / 2.0794415416798357f));
    if (bucket > 31) bucket = 31;
  }
  tab[idx] = rel_emb[bucket * HH + h];
}

// ---------------------------------------------------------------------------
// KV prep: k (b, NKS, 64) bf16 rows (zero-pad j>=NK); vt (b, 64, NKS) bf16.
// null kv at j=0; rotary on k (self-attn only). grid covers B*NKS*64/256.
// ---------------------------------------------------------------------------
__global__ __launch_bounds__(256) void kvprep_kernel(const float* __restrict__ kv_lin,
                                                     const float* __restrict__ null_kv,
                                                     u16* __restrict__ k, u16* __restrict__ vt,
                                                     int NK, int NKS, int NT, int use_rot) {
  int idx = blockIdx.x * 256 + threadIdx.x;
  int d = idx & 63;
  int rem = idx >> 6;
  int j = rem % NKS;
  int b = rem / NKS;
  float kval = 0.f, vval = 0.f;
  if (j == 0) {
    kval = null_kv[d];
    vval = null_kv[64 + d];
  } else if (j < NK) {
    int t = j - 1;
    const float* src = kv_lin + ((size_t)(b * NT + t)) * 128;
    kval = src[d];
    vval = src[64 + d];
    if (use_rot && d < 32) {
      int dd = d & 15;
      float inv = powf(10000.f, -(float)dd * (1.f / 16.f));
      float a = (float)t * inv;
      float other = src[(d < 16) ? d + 16 : d - 16];
      kval = kval * cosf(a) + ((d < 16) ? -other : other) * sinf(a);
    }
  }
  k[((size_t)b * NKS + j) * 64 + d] = f2bf(kval);
  vt[((size_t)b * 64 + d) * NKS + j] = f2bf(vval);
}

// ---------------------------------------------------------------------------
// MFMA flash attention, v2. Block = 128 thr = 2 waves; TQ=32 (16 rows/wave),
// TK=64 keys/tile. Operand-swapped QK^T (S^T in C-layout: q-row = lane&15):
// softmax reductions = 2 shuffles, one m/l scalar per lane, P packed b64 to
// LDS. Register prefetch of next K/V tile. Mask only on trailing tiles.
// ---------------------------------------------------------------------------
#define AT_STR 72

__global__ __launch_bounds__(128) void attn_mfma_kernel(
    const u16* __restrict__ q,
    const u16* __restrict__ kbuf,
    const u16* __restrict__ vtbuf,
    const float* __restrict__ bias_tab,
    u16* __restrict__ out,
    int n_keys, int NKS, int causal, int use_bias) {
  __shared__ u16 Ks[64 * AT_STR];
  __shared__ u16 Vts[64 * AT_STR];
  __shared__ u16 Sts[32 * AT_STR];
  __shared__ float bias_s[1024];

  int t = threadIdx.x;
  int wv = t >> 6, lane = t & 63;
  int lm = lane & 15, qd = lane >> 4;
  int bh = blockIdx.y;
  int b = bh >> 3, h = bh & 7;
  // heavy blocks first for causal (better tail under dynamic scheduling)
  int bx = causal ? ((int)gridDim.x - 1 - (int)blockIdx.x) : (int)blockIdx.x;
  int i0 = bx * 32;

  if (use_bias) {
    #pragma unroll
    for (int it = 0; it < 2; it++)
      *(float4*)&bias_s[(t + it * 128) * 4] =
          *(const float4*)(bias_tab + h * 1024 + (t + it * 128) * 4);
  }

  int gi_row = i0 + wv * 16 + lm;    // the q-row this lane owns in S^T layout
  frag8 qf0, qf1;
  {
    const u16* qrow = q + ((size_t)bh * NN + gi_row) * 64 + qd * 8;
    qf0 = *(const frag8*)(qrow);
    qf1 = *(const frag8*)(qrow + 32);
  }

  float m_l = -1e30f, l_l = 0.f;
  f32x4 of[4] = {};

  int num_t = causal ? (((i0 + 32) >> 6) + 1) : ((n_keys + 63) >> 6);
  const u16* kb  = kbuf  + (size_t)b * NKS * 64;
  const u16* vtb = vtbuf + (size_t)b * 64 * NKS;

  uint4 kreg[4], vreg[4];
  #pragma unroll
  for (int it = 0; it < 4; it++) {
    int pc = t + it * 128;
    int row = pc >> 3, seg = pc & 7;
    kreg[it] = *(const uint4*)(kb + (size_t)row * 64 + seg * 8);
    vreg[it] = *(const uint4*)(vtb + (size_t)row * NKS + seg * 8);
  }

  for (int tile = 0; tile < num_t; tile++) {
    int j0 = tile << 6;
    __syncthreads();   // prior tile's readers done
    #pragma unroll
    for (int it = 0; it < 4; it++) {
      int pc = t + it * 128;
      int row = pc >> 3, seg = pc & 7;
      *(uint4*)&Ks[row * AT_STR + seg * 8]  = kreg[it];
      *(uint4*)&Vts[row * AT_STR + seg * 8] = vreg[it];
    }
    if (tile + 1 < num_t) {
      int j1 = j0 + 64;
      #pragma unroll
      for (int it = 0; it < 4; it++) {
        int pc = t + it * 128;
        int row = pc >> 3, seg = pc & 7;
        kreg[it] = *(const uint4*)(kb + (size_t)(j1 + row) * 64 + seg * 8);
        vreg[it] = *(const uint4*)(vtb + (size_t)row * NKS + j1 + seg * 8);
      }
    }
    __syncthreads();

    // ---- S^T = K Q^T : D[j_local][i=lm] ----
    f32x4 sf[4];
    #pragma unroll
    for (int jf = 0; jf < 4; jf++) {
      frag8 kf0 = *(const frag8*)&Ks[(jf * 16 + lm) * AT_STR + qd * 8];
      frag8 kf1 = *(const frag8*)&Ks[(jf * 16 + lm) * AT_STR + 32 + qd * 8];
      f32x4 sa = {};
      sa = __builtin_amdgcn_mfma_f32_16x16x32_bf16(kf0, qf0, sa, 0, 0, 0);
      sa = __builtin_amdgcn_mfma_f32_16x16x32_bf16(kf1, qf1, sa, 0, 0, 0);
      sf[jf] = sa;
    }

    bool mtile = causal ? (j0 + 62 > i0) : (j0 + 63 >= n_keys);
    float sv[4][4];
    float mx = -1e30f;
    #pragma unroll
    for (int jf = 0; jf < 4; jf++) {
      #pragma unroll
      for (int r = 0; r < 4; r++) {
        int gj = j0 + jf * 16 + qd * 4 + r;
        float val = sf[jf][r];
        if (use_bias) {
          int nd = gi_row - gj; nd = nd < 0 ? 0 : nd;
          val += bias_s[nd];
        }
        if (mtile) {
          bool bad = causal ? (gj > gi_row + 1) : (gj >= n_keys);
          val = bad ? -1e30f : val;
        }
        sv[jf][r] = val;
        mx = fmaxf(mx, val);
      }
    }
    mx = fmaxf(mx, __shfl_xor(mx, 16));
    mx = fmaxf(mx, __shfl_xor(mx, 32));

    float m_new = fmaxf(m_l, mx);
    float alpha = __expf(m_l - m_new);
    m_l = m_new;
    float sum = 0.f;
    #pragma unroll
    for (int jf = 0; jf < 4; jf++) {
      float p0 = __expf(sv[jf][0] - m_new);
      float p1 = __expf(sv[jf][1] - m_new);
      float p2 = __expf(sv[jf][2] - m_new);
      float p3 = __expf(sv[jf][3] - m_new);
      sum += (p0 + p1) + (p2 + p3);
      unsigned p01 = (unsigned)f2bf(p0) | ((unsigned)f2bf(p1) << 16);
      unsigned p23 = (unsigned)f2bf(p2) | ((unsigned)f2bf(p3) << 16);
      *(uint2*)&Sts[(wv * 16 + lm) * AT_STR + jf * 16 + qd * 4] = make_uint2(p01, p23);
    }
    sum += __shfl_xor(sum, 16);
    sum += __shfl_xor(sum, 32);
    l_l = l_l * alpha + sum;

    float aR0 = __shfl(alpha, qd * 4 + 0);
    float aR1 = __shfl(alpha, qd * 4 + 1);
    float aR2 = __shfl(alpha, qd * 4 + 2);
    float aR3 = __shfl(alpha, qd * 4 + 3);

    frag8 pf0 = *(const frag8*)&Sts[(wv * 16 + lm) * AT_STR + qd * 8];
    frag8 pf1 = *(const frag8*)&Sts[(wv * 16 + lm) * AT_STR + 32 + qd * 8];
    #pragma unroll
    for (int nf = 0; nf < 4; nf++) {
      f32x4 oc = of[nf];
      oc[0] *= aR0; oc[1] *= aR1; oc[2] *= aR2; oc[3] *= aR3;
      frag8 vf0 = *(const frag8*)&Vts[(nf * 16 + lm) * AT_STR + qd * 8];
      frag8 vf1 = *(const frag8*)&Vts[(nf * 16 + lm) * AT_STR + 32 + qd * 8];
      oc = __builtin_amdgcn_mfma_f32_16x16x32_bf16(pf0, vf0, oc, 0, 0, 0);
      oc = __builtin_amdgcn_mfma_f32_16x16x32_bf16(pf1, vf1, oc, 0, 0, 0);
      of[nf] = oc;
    }
  }

  float invl = 1.f / l_l;
  float iR[4];
  iR[0] = __shfl(invl, qd * 4 + 0);
  iR[1] = __shfl(invl, qd * 4 + 1);
  iR[2] = __shfl(invl, qd * 4 + 2);
  iR[3] = __shfl(invl, qd * 4 + 3);
  #pragma unroll
  for (int nf = 0; nf < 4; nf++)
    #pragma unroll
    for (int r = 0; r < 4; r++) {
      int gi = i0 + wv * 16 + qd * 4 + r;
      out[((size_t)(b * NN + gi)) * DD + h * 64 + nf * 16 + lm] = f2bf(of[nf][r] * iR[r]);
    }
}

// ---------------------------------------------------------------------------
// Orchestration
// ---------------------------------------------------------------------------
extern "C" void kernel_launch(void* const* d_in, const int* in_sizes, int n_in,
                              void* d_out, int out_size, void* d_ws, size_t ws_size,
                              hipStream_t stream) {
  const float* in_x      = (const float*)d_in[0];
  const float* in_ctx    = (const float*)d_in[1];
  const float* rel_emb   = (const float*)d_in[2];
  const float* sa_norm_g = (const float*)d_in[3];
  const float* sa_wq     = (const float*)d_in[4];
  const float* sa_wkv    = (const float*)d_in[5];
  const float* sa_nullkv = (const float*)d_in[6];
  const float* sa_wo     = (const float*)d_in[7];
  const float* sa_out_g  = (const float*)d_in[8];
  const float* ca_norm_g = (const float*)d_in[9];
  const float* ca_ctx_g  = (const float*)d_in[10];
  const float* ca_wq     = (const float*)d_in[11];
  const float* ca_wkv    = (const float*)d_in[12];
  const float* ca_nullkv = (const float*)d_in[13];
  const float* ca_wo     = (const float*)d_in[14];
  const float* ca_out_g  = (const float*)d_in[15];
  const float* ff_norm_g = (const float*)d_in[16];
  const float* ff_w1     = (const float*)d_in[17];
  const float* ff_w2     = (const float*)d_in[18];
  const float* norm_g    = (const float*)d_in[19];

  const size_t XSZ = (size_t)BB * NN * DD;   // 2,097,152
  const int NKS_SA = 1088;                   // 17 tiles * 64
  const int NKS_CA = 576;                    // 9 tiles * 64

  float* x_cur = (float*)d_out;

  char* p = (char*)d_ws;
  float* qlin     = (float*)p;  p += XSZ * 4;                  // 8 MB
  float* kvlin    = (float*)p;  p += (size_t)524288 * 4;       // 2 MB
  float* bias_tab = (float*)p;  p += 8192 * 4;                 // 32 KB
  u16* xn_bf   = (u16*)p;  p += XSZ * 2;                       // 4 MB
  u16* ctxn_bf = (u16*)p;  p += (size_t)524288 * 2;            // 1 MB
  u16* big_bf  = (u16*)p;  p += XSZ * 2;                       // 4 MB
  u16* ffh     = (u16*)p;  p += (size_t)8388608 * 2;           // 16 MB
  u16* qbf     = (u16*)p;  p += XSZ * 2;                       // 4 MB
  u16* kbf     = (u16*)p;  p += (size_t)BB * NKS_SA * 64 * 2;  // 557 KB
  u16* vtbf    = (u16*)p;  p += (size_t)BB * NKS_SA * 64 * 2;  // 557 KB
  u16* wreg    = (u16*)p;

  const size_t S_WQ = 512 * 512, S_WKV = 512 * 128, S_WO = 512 * 512;
  const size_t S_CWQ = 512 * 512, S_CWKV = 256 * 128, S_CWO = 512 * 512;
  const size_t S_W1 = 512 * 4096, S_W2 = 2048 * 512;
  const size_t S_LAYER = S_WQ + S_WKV + S_WO + S_CWQ + S_CWKV + S_CWO + S_W1 + S_W2;

  const size_t base_bytes = (size_t)((char*)wreg - (char*)d_ws);
  const size_t need_all = base_bytes + (size_t)LL * S_LAYER * 2;
  const int all_mode = (ws_size >= need_all) ? 1 : 0;

  dim3 b256(256);

  biasprep_kernel<<<32, b256, 0, stream>>>(rel_emb, bias_tab);

  if (all_mode) {
    u16* pw = wreg;
    wtrans_kernel<<<dim3(16, 16, LL), b256, 0, stream>>>(sa_wq,  pw, 512, 512);  pw += LL * S_WQ;
    wtrans_kernel<<<dim3(4, 16, LL),  b256, 0, stream>>>(sa_wkv, pw, 512, 128);  pw += LL * S_WKV;
    wtrans_kernel<<<dim3(16, 16, LL), b256, 0, stream>>>(sa_wo,  pw, 512, 512);  pw += LL * S_WO;
    wtrans_kernel<<<dim3(16, 16, LL), b256, 0, stream>>>(ca_wq,  pw, 512, 512);  pw += LL * S_CWQ;
    wtrans_kernel<<<dim3(4, 8, LL),   b256, 0, stream>>>(ca_wkv, pw, 256, 128);  pw += LL * S_CWKV;
    wtrans_kernel<<<dim3(16, 16, LL), b256, 0, stream>>>(ca_wo,  pw, 512, 512);  pw += LL * S_CWO;
    wtrans_kernel<<<dim3(128, 16, LL),b256, 0, stream>>>(ff_w1,  pw, 512, 4096); pw += LL * S_W1;
    wtrans_kernel<<<dim3(16, 64, LL), b256, 0, stream>>>(ff_w2,  pw, 2048, 512);
  }

  hipMemcpyAsync(x_cur, in_x, sizeof(float) * XSZ, hipMemcpyDeviceToDevice, stream);

  const int ROWS = BB * NN;                  // 4096
  dim3 attn_grid(NN / 32, BB * HH);          // (32, 32), 128 threads

  for (int l = 0; l < LL; l++) {
    const float* l_sa_norm = sa_norm_g + l * DD;
    const float* l_sa_null = sa_nullkv + l * 2 * DHH;
    const float* l_sa_outg = sa_out_g + l * DD;
    const float* l_ca_norm = ca_norm_g + l * DD;
    const float* l_ca_ctxg = ca_ctx_g + l * PP;
    const float* l_ca_null = ca_nullkv + l * 2 * DHH;
    const float* l_ca_outg = ca_out_g + l * DD;
    const float* l_ff_norm = ff_norm_g + l * DD;

    u16 *t_wq, *t_wkv, *t_wo, *t_cwq, *t_cwkv, *t_cwo, *t_w1, *t_w2;
    if (all_mode) {
      u16* pw = wreg;
      t_wq   = pw + l * S_WQ;   pw += LL * S_WQ;
      t_wkv  = pw + l * S_WKV;  pw += LL * S_WKV;
      t_wo   = pw + l * S_WO;   pw += LL * S_WO;
      t_cwq  = pw + l * S_CWQ;  pw += LL * S_CWQ;
      t_cwkv = pw + l * S_CWKV; pw += LL * S_CWKV;
      t_cwo  = pw + l * S_CWO;  pw += LL * S_CWO;
      t_w1   = pw + l * S_W1;   pw += LL * S_W1;
      t_w2   = pw + l * S_W2;
    } else {
      u16* pw = wreg;
      t_wq = pw;   pw += S_WQ;
      t_wkv = pw;  pw += S_WKV;
      t_wo = pw;   pw += S_WO;
      t_cwq = pw;  pw += S_CWQ;
      t_cwkv = pw; pw += S_CWKV;
      t_cwo = pw;  pw += S_CWO;
      t_w1 = pw;   pw += S_W1;
      t_w2 = pw;
      wtrans_kernel<<<dim3(16, 16, 1), b256, 0, stream>>>(sa_wq  + (size_t)l * S_WQ,   t_wq, 512, 512);
      wtrans_kernel<<<dim3(4, 16, 1),  b256, 0, stream>>>(sa_wkv + (size_t)l * S_WKV,  t_wkv, 512, 128);
      wtrans_kernel<<<dim3(16, 16, 1), b256, 0, stream>>>(sa_wo  + (size_t)l * S_WO,   t_wo, 512, 512);
      wtrans_kernel<<<dim3(16, 16, 1), b256, 0, stream>>>(ca_wq  + (size_t)l * S_CWQ,  t_cwq, 512, 512);
      wtrans_kernel<<<dim3(4, 8, 1),   b256, 0, stream>>>(ca_wkv + (size_t)l * S_CWKV, t_cwkv, 256, 128);
      wtrans_kernel<<<dim3(16, 16, 1), b256, 0, stream>>>(ca_wo  + (size_t)l * S_CWO,  t_cwo, 512, 512);
      wtrans_kernel<<<dim3(128, 16, 1),b256, 0, stream>>>(ff_w1  + (size_t)l * S_W1,   t_w1, 512, 4096);
      wtrans_kernel<<<dim3(16, 64, 1), b256, 0, stream>>>(ff_w2  + (size_t)l * S_W2,   t_w2, 2048, 512);
    }

    // ---- self attention ----
    ln_kernel<<<ROWS, b256, 0, stream>>>(x_cur, l_sa_norm, nullptr, xn_bf, DD, 0, 1);
    mfma_gemm<128, 128, 0, 1><<<dim3(4, 32), b256, 0, stream>>>(xn_bf, t_wq, qlin, nullptr, 4096, 512, 512, qbf, 1);
    mfma_gemm<64, 64, 0, 0><<<dim3(2, 64), b256, 0, stream>>>(xn_bf, t_wkv, kvlin, nullptr, 4096, 128, 512, nullptr, 0);
    kvprep_kernel<<<BB * NKS_SA / 4, b256, 0, stream>>>(kvlin, l_sa_null, kbf, vtbf, 1025, NKS_SA, 1024, 1);
    attn_mfma_kernel<<<attn_grid, 128, 0, stream>>>(qbf, kbf, vtbf, bias_tab, big_bf, 1025, NKS_SA, 1, 1);
    mfma_gemm<128, 128, 0, 0><<<dim3(4, 32), b256, 0, stream>>>(big_bf, t_wo, qlin, nullptr, 4096, 512, 512, nullptr, 0);
    ln_kernel<<<ROWS, b256, 0, stream>>>(qlin, l_sa_outg, x_cur, x_cur, DD, 0, 0);

    // ---- cross attention ----
    ln_kernel<<<ROWS, b256, 0, stream>>>(x_cur, l_ca_norm, nullptr, xn_bf, DD, 0, 1);
    ln_kernel<<<BB * MM, b256, 0, stream>>>(in_ctx, l_ca_ctxg, nullptr, ctxn_bf, PP, 0, 1);
    mfma_gemm<128, 128, 0, 1><<<dim3(4, 32), b256, 0, stream>>>(xn_bf, t_cwq, qlin, nullptr, 4096, 512, 512, qbf, 0);
    mfma_gemm<64, 64, 0, 0><<<dim3(2, 32), b256, 0, stream>>>(ctxn_bf, t_cwkv, kvlin, nullptr, 2048, 128, 256, nullptr, 0);
    kvprep_kernel<<<BB * NKS_CA / 4, b256, 0, stream>>>(kvlin, l_ca_null, kbf, vtbf, 513, NKS_CA, 512, 0);
    attn_mfma_kernel<<<attn_grid, 128, 0, stream>>>(qbf, kbf, vtbf, nullptr, big_bf, 513, NKS_CA, 0, 0);
    mfma_gemm<128, 128, 0, 0><<<dim3(4, 32), b256, 0, stream>>>(big_bf, t_cwo, qlin, nullptr, 4096, 512, 512, nullptr, 0);
    ln_kernel<<<ROWS, b256, 0, stream>>>(qlin, l_ca_outg, x_cur, x_cur, DD, 0, 0);

    // ---- feed forward ----
    ln_kernel<<<ROWS, b256, 0, stream>>>(x_cur, l_ff_norm, nullptr, xn_bf, DD, 0, 1);
    mfma_gemm_gated<<<dim3(32, 32), b256, 0, stream>>>(xn_bf, t_w1, ffh, 4096, 2048, 512);
    mfma_gemm<128, 128, 1, 0><<<dim3(4, 32), b256, 0, stream>>>(ffh, t_w2, x_cur, x_cur, 4096, 512, 2048, nullptr, 0);
  }

  // final stable layernorm, in-place into d_out
  ln_kernel<<<ROWS, b256, 0, stream>>>(x_cur, norm_g, nullptr, x_cur, DD, 1, 0);
}

// Round 6
// 1951.939 us; speedup vs baseline: 1.1472x; 1.1472x over previous
//
#include <hip/hip_runtime.h>
#include <hip/hip_bf16.h>
#include <math.h>

// Problem constants
#define BB 4
#define NN 1024
#define MM 512
#define DD 512
#define PP 256
#define HH 8
#define DHH 64
#define LL 6
#define FFI 2048

typedef unsigned short u16;
typedef __attribute__((ext_vector_type(8))) short frag8;   // 8 bf16 (4 VGPRs)
typedef __attribute__((ext_vector_type(4))) float f32x4;   // MFMA C/D

__device__ __forceinline__ u16 f2bf(float f) {
  union { float f; unsigned u; } x; x.f = f;
  unsigned u = x.u;
  return (u16)((u + 0x7FFFu + ((u >> 16) & 1u)) >> 16);
}

// ---------------------------------------------------------------------------
// LayerNorm: y[row] = LN(x[row]) * g (+ resid[row]); obf => write bf16
// ---------------------------------------------------------------------------
__global__ __launch_bounds__(256) void ln_kernel(const float* __restrict__ x,
                                                 const float* __restrict__ g,
                                                 const float* __restrict__ resid,
                                                 void* __restrict__ y,
                                                 int cols, int stable, int obf) {
  __shared__ float sbuf[8];
  int row = blockIdx.x;
  const float* xr = x + (size_t)row * cols;
  int tid = threadIdx.x;

  float inv_mx = 1.f;
  if (stable) {
    float mx = -INFINITY;
    for (int c = tid; c < cols; c += 256) mx = fmaxf(mx, xr[c]);
    #pragma unroll
    for (int o = 32; o > 0; o >>= 1) mx = fmaxf(mx, __shfl_xor(mx, o));
    if ((tid & 63) == 0) sbuf[tid >> 6] = mx;
    __syncthreads();
    mx = fmaxf(fmaxf(sbuf[0], sbuf[1]), fmaxf(sbuf[2], sbuf[3]));
    __syncthreads();
    inv_mx = 1.f / mx;
  }

  float sum = 0.f, ss = 0.f;
  for (int c = tid; c < cols; c += 256) {
    float v = xr[c] * inv_mx;
    sum += v; ss += v * v;
  }
  #pragma unroll
  for (int o = 32; o > 0; o >>= 1) { sum += __shfl_xor(sum, o); ss += __shfl_xor(ss, o); }
  if ((tid & 63) == 0) { sbuf[tid >> 6] = sum; sbuf[4 + (tid >> 6)] = ss; }
  __syncthreads();
  sum = sbuf[0] + sbuf[1] + sbuf[2] + sbuf[3];
  ss  = sbuf[4] + sbuf[5] + sbuf[6] + sbuf[7];

  float mean = sum / cols;
  float var  = ss / cols - mean * mean;
  float r = rsqrtf(var + 1e-5f);
  for (int c = tid; c < cols; c += 256) {
    float v = (xr[c] * inv_mx - mean) * r * g[c];
    if (resid) v += resid[(size_t)row * cols + c];
    if (obf) ((u16*)y)[(size_t)row * cols + c] = f2bf(v);
    else     ((float*)y)[(size_t)row * cols + c] = v;
  }
}

// ---------------------------------------------------------------------------
// Weight convert + transpose: W (K x N fp32, layer stride K*N) -> Wt (N x K bf16)
// ---------------------------------------------------------------------------
__global__ __launch_bounds__(256) void wtrans_kernel(const float* __restrict__ W,
                                                     u16* __restrict__ Wt,
                                                     int K, int N) {
  __shared__ float tile[32][33];
  size_t lofs = (size_t)blockIdx.z * K * N;
  const float* Wl = W + lofs;
  u16* Wtl = Wt + lofs;
  int n0 = blockIdx.x * 32, k0 = blockIdx.y * 32;
  int t = threadIdx.x;
  #pragma unroll
  for (int it = 0; it < 4; it++) {
    int idx = t + it * 256;
    int r = idx >> 5, c = idx & 31;
    tile[r][c] = Wl[(size_t)(k0 + r) * N + n0 + c];
  }
  __syncthreads();
  #pragma unroll
  for (int it = 0; it < 4; it++) {
    int idx = t + it * 256;
    int r = idx >> 5, c = idx & 31;
    Wtl[(size_t)(n0 + r) * K + k0 + c] = f2bf(tile[c][r]);
  }
}

// ---------------------------------------------------------------------------
// bf16 MFMA GEMM: C(MxN) = A(MxK,bf16) @ Bt(NxK,bf16)^T  [+ res fp32]
// QEPI=1: write q bf16 (B,H,N,64) with *0.125 scale and optional rotary
//         (TN=128; rotary pairs lane-local across j=0/j=1 accumulators).
// ---------------------------------------------------------------------------
#define LSTR 40

template<int TM, int TN, int RES, int QEPI>
__global__ __launch_bounds__(256) void mfma_gemm(const u16* __restrict__ A,
                                                 const u16* __restrict__ Bt,
                                                 float* __restrict__ C,
                                                 const float* __restrict__ res,
                                                 int M, int N, int K,
                                                 u16* __restrict__ qout, int use_rot) {
  constexpr int TM2 = TM / 2, TN2 = TN / 2;
  constexpr int IT = TM2 / 16, JT = TN2 / 16;
  constexpr int ASLOT = TM * 4 / 256, BSLOT = TN * 4 / 256;
  __shared__ u16 As[TM * LSTR];
  __shared__ u16 Bs[TN * LSTR];
  int t = threadIdx.x;
  int w = t >> 6, lane = t & 63;
  int bm = blockIdx.y * TM, bn = blockIdx.x * TN;
  int wr = (w >> 1) * TM2, wc = (w & 1) * TN2;
  int lm = lane & 15, q = lane >> 4;

  f32x4 acc[IT][JT] = {};

  for (int k0 = 0; k0 < K; k0 += 32) {
    __syncthreads();
    #pragma unroll
    for (int i = 0; i < ASLOT; i++) {
      int s = t + i * 256; int m = s >> 2, c = s & 3;
      uint4 d = *(const uint4*)(A + (size_t)(bm + m) * K + k0 + c * 8);
      *(uint4*)&As[m * LSTR + c * 8] = d;
    }
    #pragma unroll
    for (int i = 0; i < BSLOT; i++) {
      int s = t + i * 256; int n = s >> 2, c = s & 3;
      uint4 d = *(const uint4*)(Bt + (size_t)(bn + n) * K + k0 + c * 8);
      *(uint4*)&Bs[n * LSTR + c * 8] = d;
    }
    __syncthreads();
    frag8 a[IT], b[JT];
    #pragma unroll
    for (int i = 0; i < IT; i++) a[i] = *(const frag8*)&As[(wr + i * 16 + lm) * LSTR + q * 8];
    #pragma unroll
    for (int j = 0; j < JT; j++) b[j] = *(const frag8*)&Bs[(wc + j * 16 + lm) * LSTR + q * 8];
    #pragma unroll
    for (int i = 0; i < IT; i++)
      #pragma unroll
      for (int j = 0; j < JT; j++)
        acc[i][j] = __builtin_amdgcn_mfma_f32_16x16x32_bf16(a[i], b[j], acc[i][j], 0, 0, 0);
  }

  if (QEPI) {
    // wave spans exactly one head (64 cols); d = j*16+lm
    int h = (bn + wc) >> 6;
    float invf = __powf(10000.f, -(float)lm * (1.f / 16.f));
    #pragma unroll
    for (int i = 0; i < IT; i++) {
      #pragma unroll
      for (int r = 0; r < 4; r++) {
        int row = bm + wr + i * 16 + q * 4 + r;
        int b2 = row >> 10, n2 = row & 1023;
        float vals[JT];
        #pragma unroll
        for (int j = 0; j < JT; j++) vals[j] = acc[i][j][r] * 0.125f;
        if (use_rot) {
          float a = (float)n2 * invf;
          float s0 = sinf(a), c0 = cosf(a);
          float v0 = vals[0], v1 = vals[1];
          vals[0] = v0 * c0 - v1 * s0;
          vals[1] = v1 * c0 + v0 * s0;
        }
        u16* dst = qout + (((size_t)(b2 * 8 + h) * 1024 + n2) << 6);
        #pragma unroll
        for (int j = 0; j < JT; j++) dst[j * 16 + lm] = f2bf(vals[j]);
      }
    }
  } else {
    #pragma unroll
    for (int i = 0; i < IT; i++)
      #pragma unroll
      for (int j = 0; j < JT; j++)
        #pragma unroll
        for (int r = 0; r < 4; r++) {
          int row = bm + wr + i * 16 + q * 4 + r;
          int col = bn + wc + j * 16 + lm;
          float v = acc[i][j][r];
          if (RES) v += res[(size_t)row * N + col];
          C[(size_t)row * N + col] = v;
        }
  }
}

// ---------------------------------------------------------------------------
// Gated FF MFMA GEMM: Bt is (2*FI) x K; out C(M x FI, bf16) = h * silu(gate)
// ---------------------------------------------------------------------------
__global__ __launch_bounds__(256) void mfma_gemm_gated(const u16* __restrict__ A,
                                                       const u16* __restrict__ Bt,
                                                       u16* __restrict__ C,
                                                       int M, int FI, int K) {
  constexpr int TM = 128, TN = 64;
  constexpr int TM2 = 64, TN2 = 32;
  constexpr int IT = 4, JT = 2;
  __shared__ u16 As[TM * LSTR];
  __shared__ u16 Bh[TN * LSTR];
  __shared__ u16 Bg[TN * LSTR];
  int t = threadIdx.x;
  int w = t >> 6, lane = t & 63;
  int bm = blockIdx.y * TM, bn = blockIdx.x * TN;
  int wr = (w >> 1) * TM2, wc = (w & 1) * TN2;
  int lm = lane & 15, q = lane >> 4;

  f32x4 ah[IT][JT] = {};
  f32x4 ag[IT][JT] = {};

  for (int k0 = 0; k0 < K; k0 += 32) {
    __syncthreads();
    #pragma unroll
    for (int i = 0; i < 2; i++) {
      int s = t + i * 256; int m = s >> 2, c = s & 3;
      uint4 d = *(const uint4*)(A + (size_t)(bm + m) * K + k0 + c * 8);
      *(uint4*)&As[m * LSTR + c * 8] = d;
    }
    {
      int s = t; int n = s >> 2, c = s & 3;
      uint4 dh = *(const uint4*)(Bt + (size_t)(bn + n) * K + k0 + c * 8);
      uint4 dg = *(const uint4*)(Bt + (size_t)(bn + FI + n) * K + k0 + c * 8);
      *(uint4*)&Bh[n * LSTR + c * 8] = dh;
      *(uint4*)&Bg[n * LSTR + c * 8] = dg;
    }
    __syncthreads();
    frag8 a[IT], bh[JT], bg[JT];
    #pragma unroll
    for (int i = 0; i < IT; i++) a[i] = *(const frag8*)&As[(wr + i * 16 + lm) * LSTR + q * 8];
    #pragma unroll
    for (int j = 0; j < JT; j++) {
      bh[j] = *(const frag8*)&Bh[(wc + j * 16 + lm) * LSTR + q * 8];
      bg[j] = *(const frag8*)&Bg[(wc + j * 16 + lm) * LSTR + q * 8];
    }
    #pragma unroll
    for (int i = 0; i < IT; i++)
      #pragma unroll
      for (int j = 0; j < JT; j++) {
        ah[i][j] = __builtin_amdgcn_mfma_f32_16x16x32_bf16(a[i], bh[j], ah[i][j], 0, 0, 0);
        ag[i][j] = __builtin_amdgcn_mfma_f32_16x16x32_bf16(a[i], bg[j], ag[i][j], 0, 0, 0);
      }
  }

  #pragma unroll
  for (int i = 0; i < IT; i++)
    #pragma unroll
    for (int j = 0; j < JT; j++)
      #pragma unroll
      for (int r = 0; r < 4; r++) {
        int row = bm + wr + i * 16 + q * 4 + r;
        int col = bn + wc + j * 16 + lm;
        float h = ah[i][j][r], g = ag[i][j][r];
        float sg = 1.f / (1.f + __expf(-g));
        C[(size_t)row * FI + col] = f2bf(h * g * sg);
      }
}

// ---------------------------------------------------------------------------
// Bias table: tab[h][delta] = rel_emb[bucket(delta)][h], delta in [0,1024)
// ---------------------------------------------------------------------------
__global__ __launch_bounds__(256) void biasprep_kernel(const float* __restrict__ rel_emb,
                                                       float* __restrict__ tab) {
  int idx = blockIdx.x * 256 + threadIdx.x;   // 8192
  int h = idx >> 10, delta = idx & 1023;
  int bucket;
  if (delta < 16) bucket = delta;
  else {
    bucket = 16 + (int)(__logf((float)delta * (1.f / 16.f)) * (16.f / 2.0794415416798357f));
    if (bucket > 31) bucket = 31;
  }
  tab[idx] = rel_emb[bucket * HH + h];
}

// ---------------------------------------------------------------------------
// KV prep: k (b, NKS, 64) bf16 rows (zero-pad j>=NK); vt (b, 64, NKS) bf16.
// ---------------------------------------------------------------------------
__global__ __launch_bounds__(256) void kvprep_kernel(const float* __restrict__ kv_lin,
                                                     const float* __restrict__ null_kv,
                                                     u16* __restrict__ k, u16* __restrict__ vt,
                                                     int NK, int NKS, int NT, int use_rot) {
  int idx = blockIdx.x * 256 + threadIdx.x;
  int d = idx & 63;
  int rem = idx >> 6;
  int j = rem % NKS;
  int b = rem / NKS;
  float kval = 0.f, vval = 0.f;
  if (j == 0) {
    kval = null_kv[d];
    vval = null_kv[64 + d];
  } else if (j < NK) {
    int t = j - 1;
    const float* src = kv_lin + ((size_t)(b * NT + t)) * 128;
    kval = src[d];
    vval = src[64 + d];
    if (use_rot && d < 32) {
      int dd = d & 15;
      float inv = powf(10000.f, -(float)dd * (1.f / 16.f));
      float a = (float)t * inv;
      float other = src[(d < 16) ? d + 16 : d - 16];
      kval = kval * cosf(a) + ((d < 16) ? -other : other) * sinf(a);
    }
  }
  k[((size_t)b * NKS + j) * 64 + d] = f2bf(kval);
  vt[((size_t)b * 64 + d) * NKS + j] = f2bf(vval);
}

// ---------------------------------------------------------------------------
// MFMA flash attention v3. Block = 256 thr = 4 waves; TQ=64 (16 rows/wave),
// TK=64 keys/tile. Operand-swapped QK^T (S^T in C-layout: q-row = lane&15):
// 2-shuffle softmax reductions, scalar per-lane m/l, packed 8B P stores.
// NO register prefetch (R5 spilled to scratch: WRITE_SIZE 4->37 MB).
// ---------------------------------------------------------------------------
#define AT_STR 72

__global__ __launch_bounds__(256) void attn_mfma_kernel(
    const u16* __restrict__ q,
    const u16* __restrict__ kbuf,
    const u16* __restrict__ vtbuf,
    const float* __restrict__ bias_tab,
    u16* __restrict__ out,
    int n_keys, int NKS, int causal, int use_bias) {
  __shared__ u16 Ks[64 * AT_STR];
  __shared__ u16 Vts[64 * AT_STR];
  __shared__ u16 Sts[64 * AT_STR];
  __shared__ float bias_s[1024];

  int t = threadIdx.x;
  int wv = t >> 6, lane = t & 63;
  int lm = lane & 15, qd = lane >> 4;
  int bh = blockIdx.y;
  int b = bh >> 3, h = bh & 7;
  // heavy blocks first for causal (better tail under dynamic scheduling)
  int bx = causal ? ((int)gridDim.x - 1 - (int)blockIdx.x) : (int)blockIdx.x;
  int i0 = bx * 64;

  if (use_bias) {
    *(float4*)&bias_s[t * 4] = *(const float4*)(bias_tab + h * 1024 + t * 4);
  }

  int gi_row = i0 + wv * 16 + lm;    // the q-row this lane owns in S^T layout
  frag8 qf0, qf1;
  {
    const u16* qrow = q + ((size_t)bh * NN + gi_row) * 64 + qd * 8;
    qf0 = *(const frag8*)(qrow);
    qf1 = *(const frag8*)(qrow + 32);
  }

  float m_l = -1e30f, l_l = 0.f;
  f32x4 of[4] = {};

  int num_t = causal ? (bx + 2) : ((n_keys + 63) >> 6);
  const u16* kb  = kbuf  + (size_t)b * NKS * 64;
  const u16* vtb = vtbuf + (size_t)b * 64 * NKS;

  for (int tile = 0; tile < num_t; tile++) {
    int j0 = tile << 6;
    __syncthreads();   // prior tile's readers done
    #pragma unroll
    for (int it = 0; it < 2; it++) {
      int pc = t + it * 256;
      int row = pc >> 3, seg = pc & 7;
      *(uint4*)&Ks[row * AT_STR + seg * 8] =
          *(const uint4*)(kb + (size_t)(j0 + row) * 64 + seg * 8);
      *(uint4*)&Vts[row * AT_STR + seg * 8] =
          *(const uint4*)(vtb + (size_t)row * NKS + j0 + seg * 8);
    }
    __syncthreads();

    // ---- S^T = K Q^T : D[key][q-row=lm] ----
    f32x4 sf[4];
    #pragma unroll
    for (int jf = 0; jf < 4; jf++) {
      frag8 kf0 = *(const frag8*)&Ks[(jf * 16 + lm) * AT_STR + qd * 8];
      frag8 kf1 = *(const frag8*)&Ks[(jf * 16 + lm) * AT_STR + 32 + qd * 8];
      f32x4 sa = {};
      sa = __builtin_amdgcn_mfma_f32_16x16x32_bf16(kf0, qf0, sa, 0, 0, 0);
      sa = __builtin_amdgcn_mfma_f32_16x16x32_bf16(kf1, qf1, sa, 0, 0, 0);
      sf[jf] = sa;
    }

    bool mtile = causal ? (j0 + 62 > i0) : (j0 + 63 >= n_keys);
    float sv[4][4];
    float mx = -1e30f;
    #pragma unroll
    for (int jf = 0; jf < 4; jf++) {
      #pragma unroll
      for (int r = 0; r < 4; r++) {
        int gj = j0 + jf * 16 + qd * 4 + r;
        float val = sf[jf][r];
        if (use_bias) {
          int nd = gi_row - gj; nd = nd < 0 ? 0 : nd;
          val += bias_s[nd];
        }
        if (mtile) {
          bool bad = causal ? (gj > gi_row + 1) : (gj >= n_keys);
          val = bad ? -1e30f : val;
        }
        sv[jf][r] = val;
        mx = fmaxf(mx, val);
      }
    }
    mx = fmaxf(mx, __shfl_xor(mx, 16));
    mx = fmaxf(mx, __shfl_xor(mx, 32));

    float m_new = fmaxf(m_l, mx);
    float alpha = __expf(m_l - m_new);
    m_l = m_new;
    float sum = 0.f;
    #pragma unroll
    for (int jf = 0; jf < 4; jf++) {
      float p0 = __expf(sv[jf][0] - m_new);
      float p1 = __expf(sv[jf][1] - m_new);
      float p2 = __expf(sv[jf][2] - m_new);
      float p3 = __expf(sv[jf][3] - m_new);
      sum += (p0 + p1) + (p2 + p3);
      unsigned p01 = (unsigned)f2bf(p0) | ((unsigned)f2bf(p1) << 16);
      unsigned p23 = (unsigned)f2bf(p2) | ((unsigned)f2bf(p3) << 16);
      *(uint2*)&Sts[(wv * 16 + lm) * AT_STR + jf * 16 + qd * 4] = make_uint2(p01, p23);
    }
    sum += __shfl_xor(sum, 16);
    sum += __shfl_xor(sum, 32);
    l_l = l_l * alpha + sum;

    float aR0 = __shfl(alpha, qd * 4 + 0);
    float aR1 = __shfl(alpha, qd * 4 + 1);
    float aR2 = __shfl(alpha, qd * 4 + 2);
    float aR3 = __shfl(alpha, qd * 4 + 3);

    frag8 pf0 = *(const frag8*)&Sts[(wv * 16 + lm) * AT_STR + qd * 8];
    frag8 pf1 = *(const frag8*)&Sts[(wv * 16 + lm) * AT_STR + 32 + qd * 8];
    #pragma unroll
    for (int nf = 0; nf < 4; nf++) {
      f32x4 oc = of[nf];
      oc[0] *= aR0; oc[1] *= aR1; oc[2] *= aR2; oc[3] *= aR3;
      frag8 vf0 = *(const frag8*)&Vts[(nf * 16 + lm) * AT_STR + qd * 8];
      frag8 vf1 = *(const frag8*)&Vts[(nf * 16 + lm) * AT_STR + 32 + qd * 8];
      oc = __builtin_amdgcn_mfma_f32_16x16x32_bf16(pf0, vf0, oc, 0, 0, 0);
      oc = __builtin_amdgcn_mfma_f32_16x16x32_bf16(pf1, vf1, oc, 0, 0, 0);
      of[nf] = oc;
    }
  }

  float invl = 1.f / l_l;
  float iR[4];
  iR[0] = __shfl(invl, qd * 4 + 0);
  iR[1] = __shfl(invl, qd * 4 + 1);
  iR[2] = __shfl(invl, qd * 4 + 2);
  iR[3] = __shfl(invl, qd * 4 + 3);
  #pragma unroll
  for (int nf = 0; nf < 4; nf++)
    #pragma unroll
    for (int r = 0; r < 4; r++) {
      int gi = i0 + wv * 16 + qd * 4 + r;
      out[((size_t)(b * NN + gi)) * DD + h * 64 + nf * 16 + lm] = f2bf(of[nf][r] * iR[r]);
    }
}

// ---------------------------------------------------------------------------
// Orchestration
// ---------------------------------------------------------------------------
extern "C" void kernel_launch(void* const* d_in, const int* in_sizes, int n_in,
                              void* d_out, int out_size, void* d_ws, size_t ws_size,
                              hipStream_t stream) {
  const float* in_x      = (const float*)d_in[0];
  const float* in_ctx    = (const float*)d_in[1];
  const float* rel_emb   = (const float*)d_in[2];
  const float* sa_norm_g = (const float*)d_in[3];
  const float* sa_wq     = (const float*)d_in[4];
  const float* sa_wkv    = (const float*)d_in[5];
  const float* sa_nullkv = (const float*)d_in[6];
  const float* sa_wo     = (const float*)d_in[7];
  const float* sa_out_g  = (const float*)d_in[8];
  const float* ca_norm_g = (const float*)d_in[9];
  const float* ca_ctx_g  = (const float*)d_in[10];
  const float* ca_wq     = (const float*)d_in[11];
  const float* ca_wkv    = (const float*)d_in[12];
  const float* ca_nullkv = (const float*)d_in[13];
  const float* ca_wo     = (const float*)d_in[14];
  const float* ca_out_g  = (const float*)d_in[15];
  const float* ff_norm_g = (const float*)d_in[16];
  const float* ff_w1     = (const float*)d_in[17];
  const float* ff_w2     = (const float*)d_in[18];
  const float* norm_g    = (const float*)d_in[19];

  const size_t XSZ = (size_t)BB * NN * DD;   // 2,097,152
  const int NKS_SA = 1088;                   // 17 tiles * 64
  const int NKS_CA = 576;                    // 9 tiles * 64

  float* x_cur = (float*)d_out;

  char* p = (char*)d_ws;
  float* qlin     = (float*)p;  p += XSZ * 4;                  // 8 MB
  float* kvlin    = (float*)p;  p += (size_t)524288 * 4;       // 2 MB
  float* bias_tab = (float*)p;  p += 8192 * 4;                 // 32 KB
  u16* xn_bf   = (u16*)p;  p += XSZ * 2;                       // 4 MB
  u16* ctxn_bf = (u16*)p;  p += (size_t)524288 * 2;            // 1 MB
  u16* big_bf  = (u16*)p;  p += XSZ * 2;                       // 4 MB
  u16* ffh     = (u16*)p;  p += (size_t)8388608 * 2;           // 16 MB
  u16* qbf     = (u16*)p;  p += XSZ * 2;                       // 4 MB
  u16* kbf     = (u16*)p;  p += (size_t)BB * NKS_SA * 64 * 2;  // 557 KB
  u16* vtbf    = (u16*)p;  p += (size_t)BB * NKS_SA * 64 * 2;  // 557 KB
  u16* wreg    = (u16*)p;

  const size_t S_WQ = 512 * 512, S_WKV = 512 * 128, S_WO = 512 * 512;
  const size_t S_CWQ = 512 * 512, S_CWKV = 256 * 128, S_CWO = 512 * 512;
  const size_t S_W1 = 512 * 4096, S_W2 = 2048 * 512;
  const size_t S_LAYER = S_WQ + S_WKV + S_WO + S_CWQ + S_CWKV + S_CWO + S_W1 + S_W2;

  const size_t base_bytes = (size_t)((char*)wreg - (char*)d_ws);
  const size_t need_all = base_bytes + (size_t)LL * S_LAYER * 2;
  const int all_mode = (ws_size >= need_all) ? 1 : 0;

  dim3 b256(256);

  biasprep_kernel<<<32, b256, 0, stream>>>(rel_emb, bias_tab);

  if (all_mode) {
    u16* pw = wreg;
    wtrans_kernel<<<dim3(16, 16, LL), b256, 0, stream>>>(sa_wq,  pw, 512, 512);  pw += LL * S_WQ;
    wtrans_kernel<<<dim3(4, 16, LL),  b256, 0, stream>>>(sa_wkv, pw, 512, 128);  pw += LL * S_WKV;
    wtrans_kernel<<<dim3(16, 16, LL), b256, 0, stream>>>(sa_wo,  pw, 512, 512);  pw += LL * S_WO;
    wtrans_kernel<<<dim3(16, 16, LL), b256, 0, stream>>>(ca_wq,  pw, 512, 512);  pw += LL * S_CWQ;
    wtrans_kernel<<<dim3(4, 8, LL),   b256, 0, stream>>>(ca_wkv, pw, 256, 128);  pw += LL * S_CWKV;
    wtrans_kernel<<<dim3(16, 16, LL), b256, 0, stream>>>(ca_wo,  pw, 512, 512);  pw += LL * S_CWO;
    wtrans_kernel<<<dim3(128, 16, LL),b256, 0, stream>>>(ff_w1,  pw, 512, 4096); pw += LL * S_W1;
    wtrans_kernel<<<dim3(16, 64, LL), b256, 0, stream>>>(ff_w2,  pw, 2048, 512);
  }

  hipMemcpyAsync(x_cur, in_x, sizeof(float) * XSZ, hipMemcpyDeviceToDevice, stream);

  const int ROWS = BB * NN;                  // 4096
  dim3 attn_grid(NN / 64, BB * HH);          // (16, 32), 256 threads

  for (int l = 0; l < LL; l++) {
    const float* l_sa_norm = sa_norm_g + l * DD;
    const float* l_sa_null = sa_nullkv + l * 2 * DHH;
    const float* l_sa_outg = sa_out_g + l * DD;
    const float* l_ca_norm = ca_norm_g + l * DD;
    const float* l_ca_ctxg = ca_ctx_g + l * PP;
    const float* l_ca_null = ca_nullkv + l * 2 * DHH;
    const float* l_ca_outg = ca_out_g + l * DD;
    const float* l_ff_norm = ff_norm_g + l * DD;

    u16 *t_wq, *t_wkv, *t_wo, *t_cwq, *t_cwkv, *t_cwo, *t_w1, *t_w2;
    if (all_mode) {
      u16* pw = wreg;
      t_wq   = pw + l * S_WQ;   pw += LL * S_WQ;
      t_wkv  = pw + l * S_WKV;  pw += LL * S_WKV;
      t_wo   = pw + l * S_WO;   pw += LL * S_WO;
      t_cwq  = pw + l * S_CWQ;  pw += LL * S_CWQ;
      t_cwkv = pw + l * S_CWKV; pw += LL * S_CWKV;
      t_cwo  = pw + l * S_CWO;  pw += LL * S_CWO;
      t_w1   = pw + l * S_W1;   pw += LL * S_W1;
      t_w2   = pw + l * S_W2;
    } else {
      u16* pw = wreg;
      t_wq = pw;   pw += S_WQ;
      t_wkv = pw;  pw += S_WKV;
      t_wo = pw;   pw += S_WO;
      t_cwq = pw;  pw += S_CWQ;
      t_cwkv = pw; pw += S_CWKV;
      t_cwo = pw;  pw += S_CWO;
      t_w1 = pw;   pw += S_W1;
      t_w2 = pw;
      wtrans_kernel<<<dim3(16, 16, 1), b256, 0, stream>>>(sa_wq  + (size_t)l * S_WQ,   t_wq, 512, 512);
      wtrans_kernel<<<dim3(4, 16, 1),  b256, 0, stream>>>(sa_wkv + (size_t)l * S_WKV,  t_wkv, 512, 128);
      wtrans_kernel<<<dim3(16, 16, 1), b256, 0, stream>>>(sa_wo  + (size_t)l * S_WO,   t_wo, 512, 512);
      wtrans_kernel<<<dim3(16, 16, 1), b256, 0, stream>>>(ca_wq  + (size_t)l * S_CWQ,  t_cwq, 512, 512);
      wtrans_kernel<<<dim3(4, 8, 1),   b256, 0, stream>>>(ca_wkv + (size_t)l * S_CWKV, t_cwkv, 256, 128);
      wtrans_kernel<<<dim3(16, 16, 1), b256, 0, stream>>>(ca_wo  + (size_t)l * S_CWO,  t_cwo, 512, 512);
      wtrans_kernel<<<dim3(128, 16, 1),b256, 0, stream>>>(ff_w1  + (size_t)l * S_W1,   t_w1, 512, 4096);
      wtrans_kernel<<<dim3(16, 64, 1), b256, 0, stream>>>(ff_w2  + (size_t)l * S_W2,   t_w2, 2048, 512);
    }

    // ---- self attention ----
    ln_kernel<<<ROWS, b256, 0, stream>>>(x_cur, l_sa_norm, nullptr, xn_bf, DD, 0, 1);
    mfma_gemm<128, 128, 0, 1><<<dim3(4, 32), b256, 0, stream>>>(xn_bf, t_wq, qlin, nullptr, 4096, 512, 512, qbf, 1);
    mfma_gemm<64, 64, 0, 0><<<dim3(2, 64), b256, 0, stream>>>(xn_bf, t_wkv, kvlin, nullptr, 4096, 128, 512, nullptr, 0);
    kvprep_kernel<<<BB * NKS_SA / 4, b256, 0, stream>>>(kvlin, l_sa_null, kbf, vtbf, 1025, NKS_SA, 1024, 1);
    attn_mfma_kernel<<<attn_grid, b256, 0, stream>>>(qbf, kbf, vtbf, bias_tab, big_bf, 1025, NKS_SA, 1, 1);
    mfma_gemm<128, 128, 0, 0><<<dim3(4, 32), b256, 0, stream>>>(big_bf, t_wo, qlin, nullptr, 4096, 512, 512, nullptr, 0);
    ln_kernel<<<ROWS, b256, 0, stream>>>(qlin, l_sa_outg, x_cur, x_cur, DD, 0, 0);

    // ---- cross attention ----
    ln_kernel<<<ROWS, b256, 0, stream>>>(x_cur, l_ca_norm, nullptr, xn_bf, DD, 0, 1);
    ln_kernel<<<BB * MM, b256, 0, stream>>>(in_ctx, l_ca_ctxg, nullptr, ctxn_bf, PP, 0, 1);
    mfma_gemm<128, 128, 0, 1><<<dim3(4, 32), b256, 0, stream>>>(xn_bf, t_cwq, qlin, nullptr, 4096, 512, 512, qbf, 0);
    mfma_gemm<64, 64, 0, 0><<<dim3(2, 32), b256, 0, stream>>>(ctxn_bf, t_cwkv, kvlin, nullptr, 2048, 128, 256, nullptr, 0);
    kvprep_kernel<<<BB * NKS_CA / 4, b256, 0, stream>>>(kvlin, l_ca_null, kbf, vtbf, 513, NKS_CA, 512, 0);
    attn_mfma_kernel<<<attn_grid, b256, 0, stream>>>(qbf, kbf, vtbf, nullptr, big_bf, 513, NKS_CA, 0, 0);
    mfma_gemm<128, 128, 0, 0><<<dim3(4, 32), b256, 0, stream>>>(big_bf, t_cwo, qlin, nullptr, 4096, 512, 512, nullptr, 0);
    ln_kernel<<<ROWS, b256, 0, stream>>>(qlin, l_ca_outg, x_cur, x_cur, DD, 0, 0);

    // ---- feed forward ----
    ln_kernel<<<ROWS, b256, 0, stream>>>(x_cur, l_ff_norm, nullptr, xn_bf, DD, 0, 1);
    mfma_gemm_gated<<<dim3(32, 32), b256, 0, stream>>>(xn_bf, t_w1, ffh, 4096, 2048, 512);
    mfma_gemm<128, 128, 1, 0><<<dim3(4, 32), b256, 0, stream>>>(ffh, t_w2, x_cur, x_cur, 4096, 512, 2048, nullptr, 0);
  }

  // final stable layernorm, in-place into d_out
  ln_kernel<<<ROWS, b256, 0, stream>>>(x_cur, norm_g, nullptr, x_cur, DD, 1, 0);
}

// Round 7
// 1681.937 us; speedup vs baseline: 1.3314x; 1.1605x over previous
//
#include <hip/hip_runtime.h>
#include <hip/hip_bf16.h>
#include <math.h>

// Problem constants
#define BB 4
#define NN 1024
#define MM 512
#define DD 512
#define PP 256
#define HH 8
#define DHH 64
#define LL 6
#define FFI 2048

typedef unsigned short u16;
typedef __attribute__((ext_vector_type(8))) short frag8;   // 8 bf16 (4 VGPRs)
typedef __attribute__((ext_vector_type(4))) float f32x4;   // MFMA C/D

__device__ __forceinline__ u16 f2bf(float f) {
  union { float f; unsigned u; } x; x.f = f;
  unsigned u = x.u;
  return (u16)((u + 0x7FFFu + ((u >> 16) & 1u)) >> 16);
}

__device__ __forceinline__ unsigned pack_bf16(float a, float b) {
  __hip_bfloat162 h2 = __float22bfloat162_rn(make_float2(a, b));
  union { __hip_bfloat162 h; unsigned u; } cv; cv.h = h2; return cv.u;
}

// ---------------------------------------------------------------------------
// LayerNorm: y[row] = LN(x[row]) * g (+ resid); g==null -> gain 1.
// ---------------------------------------------------------------------------
__global__ __launch_bounds__(256) void ln_kernel(const float* __restrict__ x,
                                                 const float* __restrict__ g,
                                                 const float* __restrict__ resid,
                                                 void* __restrict__ y,
                                                 int cols, int stable, int obf) {
  __shared__ float sbuf[8];
  int row = blockIdx.x;
  const float* xr = x + (size_t)row * cols;
  int tid = threadIdx.x;

  float inv_mx = 1.f;
  if (stable) {
    float mx = -INFINITY;
    for (int c = tid; c < cols; c += 256) mx = fmaxf(mx, xr[c]);
    #pragma unroll
    for (int o = 32; o > 0; o >>= 1) mx = fmaxf(mx, __shfl_xor(mx, o));
    if ((tid & 63) == 0) sbuf[tid >> 6] = mx;
    __syncthreads();
    mx = fmaxf(fmaxf(sbuf[0], sbuf[1]), fmaxf(sbuf[2], sbuf[3]));
    __syncthreads();
    inv_mx = 1.f / mx;
  }

  float sum = 0.f, ss = 0.f;
  for (int c = tid; c < cols; c += 256) {
    float v = xr[c] * inv_mx;
    sum += v; ss += v * v;
  }
  #pragma unroll
  for (int o = 32; o > 0; o >>= 1) { sum += __shfl_xor(sum, o); ss += __shfl_xor(ss, o); }
  if ((tid & 63) == 0) { sbuf[tid >> 6] = sum; sbuf[4 + (tid >> 6)] = ss; }
  __syncthreads();
  sum = sbuf[0] + sbuf[1] + sbuf[2] + sbuf[3];
  ss  = sbuf[4] + sbuf[5] + sbuf[6] + sbuf[7];

  float mean = sum / cols;
  float var  = ss / cols - mean * mean;
  float r = rsqrtf(var + 1e-5f);
  for (int c = tid; c < cols; c += 256) {
    float gv = g ? g[c] : 1.f;
    float v = (xr[c] * inv_mx - mean) * r * gv;
    if (resid) v += resid[(size_t)row * cols + c];
    if (obf) ((u16*)y)[(size_t)row * cols + c] = f2bf(v);
    else     ((float*)y)[(size_t)row * cols + c] = v;
  }
}

// ---------------------------------------------------------------------------
// Fused: t = LN(q)*g_out + x;  x = t;  xn = bf16(LN(t))   (cols = 512 fixed)
// ---------------------------------------------------------------------------
__global__ __launch_bounds__(256) void ln_fuse2_kernel(const float* __restrict__ qin,
                                                       const float* __restrict__ g_out,
                                                       float* __restrict__ x,
                                                       u16* __restrict__ xn) {
  __shared__ float sb[8];
  int row = blockIdx.x;
  int tid = threadIdx.x;
  float2 q2 = *(const float2*)(qin + (size_t)row * 512 + tid * 2);

  float sum = q2.x + q2.y, ss = q2.x * q2.x + q2.y * q2.y;
  #pragma unroll
  for (int o = 32; o > 0; o >>= 1) { sum += __shfl_xor(sum, o); ss += __shfl_xor(ss, o); }
  if ((tid & 63) == 0) { sb[tid >> 6] = sum; sb[4 + (tid >> 6)] = ss; }
  __syncthreads();
  sum = sb[0] + sb[1] + sb[2] + sb[3];
  ss  = sb[4] + sb[5] + sb[6] + sb[7];
  float mu = sum * (1.f / 512.f);
  float r  = rsqrtf(ss * (1.f / 512.f) - mu * mu + 1e-5f);

  float2 x2 = *(const float2*)(x + (size_t)row * 512 + tid * 2);
  float2 g2 = *(const float2*)(g_out + tid * 2);
  float t0 = (q2.x - mu) * r * g2.x + x2.x;
  float t1 = (q2.y - mu) * r * g2.y + x2.y;

  __syncthreads();
  float sum2 = t0 + t1, ss2 = t0 * t0 + t1 * t1;
  #pragma unroll
  for (int o = 32; o > 0; o >>= 1) { sum2 += __shfl_xor(sum2, o); ss2 += __shfl_xor(ss2, o); }
  if ((tid & 63) == 0) { sb[tid >> 6] = sum2; sb[4 + (tid >> 6)] = ss2; }
  __syncthreads();
  sum2 = sb[0] + sb[1] + sb[2] + sb[3];
  ss2  = sb[4] + sb[5] + sb[6] + sb[7];
  float mu2 = sum2 * (1.f / 512.f);
  float r2  = rsqrtf(ss2 * (1.f / 512.f) - mu2 * mu2 + 1e-5f);

  *(float2*)(x + (size_t)row * 512 + tid * 2) = make_float2(t0, t1);
  ((unsigned*)xn)[(size_t)row * 256 + tid] = pack_bf16((t0 - mu2) * r2, (t1 - mu2) * r2);
}

// ---------------------------------------------------------------------------
// Weight convert + transpose (+ optional per-k gain fold):
// W (K x N fp32) -> Wt (N x K bf16), Wt[n][k] = W[k][n] * g[k]
// ---------------------------------------------------------------------------
__global__ __launch_bounds__(256) void wtrans_kernel(const float* __restrict__ W,
                                                     const float* __restrict__ g,
                                                     u16* __restrict__ Wt,
                                                     int K, int N) {
  __shared__ float tile[32][33];
  size_t lofs = (size_t)blockIdx.z * K * N;
  const float* Wl = W + lofs;
  const float* gl = g ? g + (size_t)blockIdx.z * K : nullptr;
  u16* Wtl = Wt + lofs;
  int n0 = blockIdx.x * 32, k0 = blockIdx.y * 32;
  int t = threadIdx.x;
  #pragma unroll
  for (int it = 0; it < 4; it++) {
    int idx = t + it * 256;
    int r = idx >> 5, c = idx & 31;
    tile[r][c] = Wl[(size_t)(k0 + r) * N + n0 + c];
  }
  __syncthreads();
  #pragma unroll
  for (int it = 0; it < 4; it++) {
    int idx = t + it * 256;
    int r = idx >> 5, c = idx & 31;
    float gv = gl ? gl[k0 + c] : 1.f;
    Wtl[(size_t)(n0 + r) * K + k0 + c] = f2bf(tile[c][r] * gv);
  }
}

// ---------------------------------------------------------------------------
// bf16 MFMA GEMM: C(MxN) = A(MxK,bf16) @ Bt(NxK,bf16)^T  [+ res fp32]
// QEPI=1: write q bf16 (B,H,N,64) with *0.125 scale and optional rotary.
// ---------------------------------------------------------------------------
#define LSTR 40

template<int TM, int TN, int RES, int QEPI>
__global__ __launch_bounds__(256) void mfma_gemm(const u16* __restrict__ A,
                                                 const u16* __restrict__ Bt,
                                                 float* __restrict__ C,
                                                 const float* __restrict__ res,
                                                 int M, int N, int K,
                                                 u16* __restrict__ qout, int use_rot) {
  constexpr int TM2 = TM / 2, TN2 = TN / 2;
  constexpr int IT = TM2 / 16, JT = TN2 / 16;
  constexpr int ASLOT = TM * 4 / 256, BSLOT = TN * 4 / 256;
  __shared__ u16 As[TM * LSTR];
  __shared__ u16 Bs[TN * LSTR];
  int t = threadIdx.x;
  int w = t >> 6, lane = t & 63;
  int bm = blockIdx.y * TM, bn = blockIdx.x * TN;
  int wr = (w >> 1) * TM2, wc = (w & 1) * TN2;
  int lm = lane & 15, q = lane >> 4;

  f32x4 acc[IT][JT] = {};

  for (int k0 = 0; k0 < K; k0 += 32) {
    __syncthreads();
    #pragma unroll
    for (int i = 0; i < ASLOT; i++) {
      int s = t + i * 256; int m = s >> 2, c = s & 3;
      uint4 d = *(const uint4*)(A + (size_t)(bm + m) * K + k0 + c * 8);
      *(uint4*)&As[m * LSTR + c * 8] = d;
    }
    #pragma unroll
    for (int i = 0; i < BSLOT; i++) {
      int s = t + i * 256; int n = s >> 2, c = s & 3;
      uint4 d = *(const uint4*)(Bt + (size_t)(bn + n) * K + k0 + c * 8);
      *(uint4*)&Bs[n * LSTR + c * 8] = d;
    }
    __syncthreads();
    frag8 a[IT], b[JT];
    #pragma unroll
    for (int i = 0; i < IT; i++) a[i] = *(const frag8*)&As[(wr + i * 16 + lm) * LSTR + q * 8];
    #pragma unroll
    for (int j = 0; j < JT; j++) b[j] = *(const frag8*)&Bs[(wc + j * 16 + lm) * LSTR + q * 8];
    #pragma unroll
    for (int i = 0; i < IT; i++)
      #pragma unroll
      for (int j = 0; j < JT; j++)
        acc[i][j] = __builtin_amdgcn_mfma_f32_16x16x32_bf16(a[i], b[j], acc[i][j], 0, 0, 0);
  }

  if (QEPI) {
    int h = (bn + wc) >> 6;
    float invf = __powf(10000.f, -(float)lm * (1.f / 16.f));
    #pragma unroll
    for (int i = 0; i < IT; i++) {
      #pragma unroll
      for (int r = 0; r < 4; r++) {
        int row = bm + wr + i * 16 + q * 4 + r;
        int b2 = row >> 10, n2 = row & 1023;
        float vals[JT];
        #pragma unroll
        for (int j = 0; j < JT; j++) vals[j] = acc[i][j][r] * 0.125f;
        if (use_rot) {
          float a = (float)n2 * invf;
          float s0 = sinf(a), c0 = cosf(a);
          float v0 = vals[0], v1 = vals[1];
          vals[0] = v0 * c0 - v1 * s0;
          vals[1] = v1 * c0 + v0 * s0;
        }
        u16* dst = qout + (((size_t)(b2 * 8 + h) * 1024 + n2) << 6);
        #pragma unroll
        for (int j = 0; j < JT; j++) dst[j * 16 + lm] = f2bf(vals[j]);
      }
    }
  } else {
    #pragma unroll
    for (int i = 0; i < IT; i++)
      #pragma unroll
      for (int j = 0; j < JT; j++)
        #pragma unroll
        for (int r = 0; r < 4; r++) {
          int row = bm + wr + i * 16 + q * 4 + r;
          int col = bn + wc + j * 16 + lm;
          float v = acc[i][j][r];
          if (RES) v += res[(size_t)row * N + col];
          C[(size_t)row * N + col] = v;
        }
  }
}

// ---------------------------------------------------------------------------
// Gated FF MFMA GEMM: Bt is (2*FI) x K; out C(M x FI, bf16) = h * silu(gate)
// ---------------------------------------------------------------------------
__global__ __launch_bounds__(256) void mfma_gemm_gated(const u16* __restrict__ A,
                                                       const u16* __restrict__ Bt,
                                                       u16* __restrict__ C,
                                                       int M, int FI, int K) {
  constexpr int TM = 128, TN = 64;
  constexpr int TM2 = 64, TN2 = 32;
  constexpr int IT = 4, JT = 2;
  __shared__ u16 As[TM * LSTR];
  __shared__ u16 Bh[TN * LSTR];
  __shared__ u16 Bg[TN * LSTR];
  int t = threadIdx.x;
  int w = t >> 6, lane = t & 63;
  int bm = blockIdx.y * TM, bn = blockIdx.x * TN;
  int wr = (w >> 1) * TM2, wc = (w & 1) * TN2;
  int lm = lane & 15, q = lane >> 4;

  f32x4 ah[IT][JT] = {};
  f32x4 ag[IT][JT] = {};

  for (int k0 = 0; k0 < K; k0 += 32) {
    __syncthreads();
    #pragma unroll
    for (int i = 0; i < 2; i++) {
      int s = t + i * 256; int m = s >> 2, c = s & 3;
      uint4 d = *(const uint4*)(A + (size_t)(bm + m) * K + k0 + c * 8);
      *(uint4*)&As[m * LSTR + c * 8] = d;
    }
    {
      int s = t; int n = s >> 2, c = s & 3;
      uint4 dh = *(const uint4*)(Bt + (size_t)(bn + n) * K + k0 + c * 8);
      uint4 dg = *(const uint4*)(Bt + (size_t)(bn + FI + n) * K + k0 + c * 8);
      *(uint4*)&Bh[n * LSTR + c * 8] = dh;
      *(uint4*)&Bg[n * LSTR + c * 8] = dg;
    }
    __syncthreads();
    frag8 a[IT], bh[JT], bg[JT];
    #pragma unroll
    for (int i = 0; i < IT; i++) a[i] = *(const frag8*)&As[(wr + i * 16 + lm) * LSTR + q * 8];
    #pragma unroll
    for (int j = 0; j < JT; j++) {
      bh[j] = *(const frag8*)&Bh[(wc + j * 16 + lm) * LSTR + q * 8];
      bg[j] = *(const frag8*)&Bg[(wc + j * 16 + lm) * LSTR + q * 8];
    }
    #pragma unroll
    for (int i = 0; i < IT; i++)
      #pragma unroll
      for (int j = 0; j < JT; j++) {
        ah[i][j] = __builtin_amdgcn_mfma_f32_16x16x32_bf16(a[i], bh[j], ah[i][j], 0, 0, 0);
        ag[i][j] = __builtin_amdgcn_mfma_f32_16x16x32_bf16(a[i], bg[j], ag[i][j], 0, 0, 0);
      }
  }

  #pragma unroll
  for (int i = 0; i < IT; i++)
    #pragma unroll
    for (int j = 0; j < JT; j++)
      #pragma unroll
      for (int r = 0; r < 4; r++) {
        int row = bm + wr + i * 16 + q * 4 + r;
        int col = bn + wc + j * 16 + lm;
        float h = ah[i][j][r], g = ag[i][j][r];
        float sg = 1.f / (1.f + __expf(-g));
        C[(size_t)row * FI + col] = f2bf(h * g * sg);
      }
}

// ---------------------------------------------------------------------------
// Bias table: tab[h][delta] = rel_emb[bucket(delta)][h], delta in [0,1024)
// ---------------------------------------------------------------------------
__global__ __launch_bounds__(256) void biasprep_kernel(const float* __restrict__ rel_emb,
                                                       float* __restrict__ tab) {
  int idx = blockIdx.x * 256 + threadIdx.x;   // 8192
  int h = idx >> 10, delta = idx & 1023;
  int bucket;
  if (delta < 16) bucket = delta;
  else {
    bucket = 16 + (int)(__logf((float)delta * (1.f / 16.f)) * (16.f / 2.0794415416798357f));
    if (bucket > 31) bucket = 31;
  }
  tab[idx] = rel_emb[bucket * HH + h];
}

// ---------------------------------------------------------------------------
// KV prep: k (b, NKS, 64) bf16 rows (zero-pad j>=NK); vt (b, 64, NKS) bf16.
// ---------------------------------------------------------------------------
__global__ __launch_bounds__(256) void kvprep_kernel(const float* __restrict__ kv_lin,
                                                     const float* __restrict__ null_kv,
                                                     u16* __restrict__ k, u16* __restrict__ vt,
                                                     int NK, int NKS, int NT, int use_rot) {
  int idx = blockIdx.x * 256 + threadIdx.x;
  int d = idx & 63;
  int rem = idx >> 6;
  int j = rem % NKS;
  int b = rem / NKS;
  float kval = 0.f, vval = 0.f;
  if (j == 0) {
    kval = null_kv[d];
    vval = null_kv[64 + d];
  } else if (j < NK) {
    int t = j - 1;
    const float* src = kv_lin + ((size_t)(b * NT + t)) * 128;
    kval = src[d];
    vval = src[64 + d];
    if (use_rot && d < 32) {
      int dd = d & 15;
      float inv = powf(10000.f, -(float)dd * (1.f / 16.f));
      float a = (float)t * inv;
      float other = src[(d < 16) ? d + 16 : d - 16];
      kval = kval * cosf(a) + ((d < 16) ? -other : other) * sinf(a);
    }
  }
  k[((size_t)b * NKS + j) * 64 + d] = f2bf(kval);
  vt[((size_t)b * 64 + d) * NKS + j] = f2bf(vval);
}

// ---------------------------------------------------------------------------
// MFMA flash attention v4. Block = 128 thr = 2 waves; TQ=32, TK=64.
// Operand-swapped QK^T; far-tile constant-bias fast path (bucket saturates
// at delta>=113); packed bf16 conversions; no register prefetch.
// ---------------------------------------------------------------------------
#define AT_STR 72

__global__ __launch_bounds__(128) void attn_mfma_kernel(
    const u16* __restrict__ q,
    const u16* __restrict__ kbuf,
    const u16* __restrict__ vtbuf,
    const float* __restrict__ bias_tab,
    u16* __restrict__ out,
    int n_keys, int NKS, int causal, int use_bias) {
  __shared__ u16 Ks[64 * AT_STR];
  __shared__ u16 Vts[64 * AT_STR];
  __shared__ u16 Sts[32 * AT_STR];
  __shared__ float bias_s[1024];

  int t = threadIdx.x;
  int wv = t >> 6, lane = t & 63;
  int lm = lane & 15, qd = lane >> 4;
  int bh = blockIdx.y;
  int b = bh >> 3, h = bh & 7;
  // heavy blocks first for causal (better tail under dynamic scheduling)
  int bx = causal ? ((int)gridDim.x - 1 - (int)blockIdx.x) : (int)blockIdx.x;
  int i0 = bx * 32;

  float b31 = 0.f;
  if (use_bias) {
    #pragma unroll
    for (int it = 0; it < 2; it++)
      *(float4*)&bias_s[(t + it * 128) * 4] =
          *(const float4*)(bias_tab + h * 1024 + (t + it * 128) * 4);
    b31 = bias_tab[h * 1024 + 1023];   // saturated bucket value
  }

  int gi_row = i0 + wv * 16 + lm;    // the q-row this lane owns in S^T layout
  frag8 qf0, qf1;
  {
    const u16* qrow = q + ((size_t)bh * NN + gi_row) * 64 + qd * 8;
    qf0 = *(const frag8*)(qrow);
    qf1 = *(const frag8*)(qrow + 32);
  }

  float m_l = -1e30f, l_l = 0.f;
  f32x4 of[4] = {};

  int num_t = causal ? (((i0 + 32) >> 6) + 1) : ((n_keys + 63) >> 6);
  const u16* kb  = kbuf  + (size_t)b * NKS * 64;
  const u16* vtb = vtbuf + (size_t)b * 64 * NKS;

  for (int tile = 0; tile < num_t; tile++) {
    int j0 = tile << 6;
    __syncthreads();   // prior tile's readers done
    #pragma unroll
    for (int it = 0; it < 4; it++) {
      int pc = t + it * 128;
      int row = pc >> 3, seg = pc & 7;
      *(uint4*)&Ks[row * AT_STR + seg * 8] =
          *(const uint4*)(kb + (size_t)(j0 + row) * 64 + seg * 8);
      *(uint4*)&Vts[row * AT_STR + seg * 8] =
          *(const uint4*)(vtb + (size_t)row * NKS + j0 + seg * 8);
    }
    __syncthreads();

    // ---- S^T = K Q^T : D[key][q-row=lm] ----
    f32x4 sf[4];
    #pragma unroll
    for (int jf = 0; jf < 4; jf++) {
      frag8 kf0 = *(const frag8*)&Ks[(jf * 16 + lm) * AT_STR + qd * 8];
      frag8 kf1 = *(const frag8*)&Ks[(jf * 16 + lm) * AT_STR + 32 + qd * 8];
      f32x4 sa = {};
      sa = __builtin_amdgcn_mfma_f32_16x16x32_bf16(kf0, qf0, sa, 0, 0, 0);
      sa = __builtin_amdgcn_mfma_f32_16x16x32_bf16(kf1, qf1, sa, 0, 0, 0);
      sf[jf] = sa;
    }

    float sv[4][4];
    float mx = -1e30f;
    bool far = use_bias && ((i0 + wv * 16) - (j0 + 63) >= 116);  // wave-uniform
    if (far) {
      // entire wave-tile: bias == rel_emb[31][h], no mask possible
      #pragma unroll
      for (int jf = 0; jf < 4; jf++)
        #pragma unroll
        for (int r = 0; r < 4; r++) {
          float val = sf[jf][r] + b31;
          sv[jf][r] = val;
          mx = fmaxf(mx, val);
        }
    } else {
      bool mtile = causal ? (j0 + 62 > i0) : (j0 + 63 >= n_keys);
      #pragma unroll
      for (int jf = 0; jf < 4; jf++) {
        #pragma unroll
        for (int r = 0; r < 4; r++) {
          int gj = j0 + jf * 16 + qd * 4 + r;
          float val = sf[jf][r];
          if (use_bias) {
            int nd = gi_row - gj; nd = nd < 0 ? 0 : nd;
            val += bias_s[nd];
          }
          if (mtile) {
            bool bad = causal ? (gj > gi_row + 1) : (gj >= n_keys);
            val = bad ? -1e30f : val;
          }
          sv[jf][r] = val;
          mx = fmaxf(mx, val);
        }
      }
    }
    mx = fmaxf(mx, __shfl_xor(mx, 16));
    mx = fmaxf(mx, __shfl_xor(mx, 32));

    float m_new = fmaxf(m_l, mx);
    float alpha = __expf(m_l - m_new);
    m_l = m_new;
    float sum = 0.f;
    #pragma unroll
    for (int jf = 0; jf < 4; jf++) {
      float p0 = __expf(sv[jf][0] - m_new);
      float p1 = __expf(sv[jf][1] - m_new);
      float p2 = __expf(sv[jf][2] - m_new);
      float p3 = __expf(sv[jf][3] - m_new);
      sum += (p0 + p1) + (p2 + p3);
      *(uint2*)&Sts[(wv * 16 + lm) * AT_STR + jf * 16 + qd * 4] =
          make_uint2(pack_bf16(p0, p1), pack_bf16(p2, p3));
    }
    sum += __shfl_xor(sum, 16);
    sum += __shfl_xor(sum, 32);
    l_l = l_l * alpha + sum;

    float aR0 = __shfl(alpha, qd * 4 + 0);
    float aR1 = __shfl(alpha, qd * 4 + 1);
    float aR2 = __shfl(alpha, qd * 4 + 2);
    float aR3 = __shfl(alpha, qd * 4 + 3);

    frag8 pf0 = *(const frag8*)&Sts[(wv * 16 + lm) * AT_STR + qd * 8];
    frag8 pf1 = *(const frag8*)&Sts[(wv * 16 + lm) * AT_STR + 32 + qd * 8];
    #pragma unroll
    for (int nf = 0; nf < 4; nf++) {
      f32x4 oc = of[nf];
      oc[0] *= aR0; oc[1] *= aR1; oc[2] *= aR2; oc[3] *= aR3;
      frag8 vf0 = *(const frag8*)&Vts[(nf * 16 + lm) * AT_STR + qd * 8];
      frag8 vf1 = *(const frag8*)&Vts[(nf * 16 + lm) * AT_STR + 32 + qd * 8];
      oc = __builtin_amdgcn_mfma_f32_16x16x32_bf16(pf0, vf0, oc, 0, 0, 0);
      oc = __builtin_amdgcn_mfma_f32_16x16x32_bf16(pf1, vf1, oc, 0, 0, 0);
      of[nf] = oc;
    }
  }

  float invl = 1.f / l_l;
  float iR[4];
  iR[0] = __shfl(invl, qd * 4 + 0);
  iR[1] = __shfl(invl, qd * 4 + 1);
  iR[2] = __shfl(invl, qd * 4 + 2);
  iR[3] = __shfl(invl, qd * 4 + 3);
  #pragma unroll
  for (int nf = 0; nf < 4; nf++)
    #pragma unroll
    for (int r = 0; r < 4; r++) {
      int gi = i0 + wv * 16 + qd * 4 + r;
      out[((size_t)(b * NN + gi)) * DD + h * 64 + nf * 16 + lm] = f2bf(of[nf][r] * iR[r]);
    }
}

// ---------------------------------------------------------------------------
// Orchestration
// ---------------------------------------------------------------------------
extern "C" void kernel_launch(void* const* d_in, const int* in_sizes, int n_in,
                              void* d_out, int out_size, void* d_ws, size_t ws_size,
                              hipStream_t stream) {
  const float* in_x      = (const float*)d_in[0];
  const float* in_ctx    = (const float*)d_in[1];
  const float* rel_emb   = (const float*)d_in[2];
  const float* sa_norm_g = (const float*)d_in[3];
  const float* sa_wq     = (const float*)d_in[4];
  const float* sa_wkv    = (const float*)d_in[5];
  const float* sa_nullkv = (const float*)d_in[6];
  const float* sa_wo     = (const float*)d_in[7];
  const float* sa_out_g  = (const float*)d_in[8];
  const float* ca_norm_g = (const float*)d_in[9];
  const float* ca_ctx_g  = (const float*)d_in[10];
  const float* ca_wq     = (const float*)d_in[11];
  const float* ca_wkv    = (const float*)d_in[12];
  const float* ca_nullkv = (const float*)d_in[13];
  const float* ca_wo     = (const float*)d_in[14];
  const float* ca_out_g  = (const float*)d_in[15];
  const float* ff_norm_g = (const float*)d_in[16];
  const float* ff_w1     = (const float*)d_in[17];
  const float* ff_w2     = (const float*)d_in[18];
  const float* norm_g    = (const float*)d_in[19];

  const size_t XSZ = (size_t)BB * NN * DD;   // 2,097,152
  const int NKS_SA = 1088;                   // 17 tiles * 64
  const int NKS_CA = 576;                    // 9 tiles * 64

  float* x_cur = (float*)d_out;

  char* p = (char*)d_ws;
  float* qlin     = (float*)p;  p += XSZ * 4;                  // 8 MB
  float* kvlin    = (float*)p;  p += (size_t)524288 * 4;       // 2 MB
  float* bias_tab = (float*)p;  p += 8192 * 4;                 // 32 KB
  u16* xn_bf   = (u16*)p;  p += XSZ * 2;                       // 4 MB
  u16* ctxn_bf = (u16*)p;  p += (size_t)524288 * 2;            // 1 MB
  u16* big_bf  = (u16*)p;  p += XSZ * 2;                       // 4 MB
  u16* ffh     = (u16*)p;  p += (size_t)8388608 * 2;           // 16 MB
  u16* qbf     = (u16*)p;  p += XSZ * 2;                       // 4 MB
  u16* kbf     = (u16*)p;  p += (size_t)BB * NKS_SA * 64 * 2;  // 557 KB
  u16* vtbf    = (u16*)p;  p += (size_t)BB * NKS_SA * 64 * 2;  // 557 KB
  u16* wreg    = (u16*)p;

  const size_t S_WQ = 512 * 512, S_WKV = 512 * 128, S_WO = 512 * 512;
  const size_t S_CWQ = 512 * 512, S_CWKV = 256 * 128, S_CWO = 512 * 512;
  const size_t S_W1 = 512 * 4096, S_W2 = 2048 * 512;
  const size_t S_LAYER = S_WQ + S_WKV + S_WO + S_CWQ + S_CWKV + S_CWO + S_W1 + S_W2;

  const size_t base_bytes = (size_t)((char*)wreg - (char*)d_ws);
  const size_t need_all = base_bytes + (size_t)LL * S_LAYER * 2;
  const int all_mode = (ws_size >= need_all) ? 1 : 0;

  dim3 b256(256);

  biasprep_kernel<<<32, b256, 0, stream>>>(rel_emb, bias_tab);

  if (all_mode) {
    u16* pw = wreg;
    wtrans_kernel<<<dim3(16, 16, LL), b256, 0, stream>>>(sa_wq,  sa_norm_g, pw, 512, 512);  pw += LL * S_WQ;
    wtrans_kernel<<<dim3(4, 16, LL),  b256, 0, stream>>>(sa_wkv, sa_norm_g, pw, 512, 128);  pw += LL * S_WKV;
    wtrans_kernel<<<dim3(16, 16, LL), b256, 0, stream>>>(sa_wo,  nullptr,   pw, 512, 512);  pw += LL * S_WO;
    wtrans_kernel<<<dim3(16, 16, LL), b256, 0, stream>>>(ca_wq,  ca_norm_g, pw, 512, 512);  pw += LL * S_CWQ;
    wtrans_kernel<<<dim3(4, 8, LL),   b256, 0, stream>>>(ca_wkv, ca_ctx_g,  pw, 256, 128);  pw += LL * S_CWKV;
    wtrans_kernel<<<dim3(16, 16, LL), b256, 0, stream>>>(ca_wo,  nullptr,   pw, 512, 512);  pw += LL * S_CWO;
    wtrans_kernel<<<dim3(128, 16, LL),b256, 0, stream>>>(ff_w1,  ff_norm_g, pw, 512, 4096); pw += LL * S_W1;
    wtrans_kernel<<<dim3(16, 64, LL), b256, 0, stream>>>(ff_w2,  nullptr,   pw, 2048, 512);
  }

  hipMemcpyAsync(x_cur, in_x, sizeof(float) * XSZ, hipMemcpyDeviceToDevice, stream);

  const int ROWS = BB * NN;                  // 4096
  dim3 attn_grid(NN / 32, BB * HH);          // (32, 32), 128 threads

  // ctx LN once (plain; per-layer gains folded into t_cwkv)
  ln_kernel<<<BB * MM, b256, 0, stream>>>(in_ctx, nullptr, nullptr, ctxn_bf, PP, 0, 1);

  for (int l = 0; l < LL; l++) {
    const float* l_sa_null = sa_nullkv + l * 2 * DHH;
    const float* l_sa_outg = sa_out_g + l * DD;
    const float* l_ca_null = ca_nullkv + l * 2 * DHH;
    const float* l_ca_outg = ca_out_g + l * DD;

    u16 *t_wq, *t_wkv, *t_wo, *t_cwq, *t_cwkv, *t_cwo, *t_w1, *t_w2;
    if (all_mode) {
      u16* pw = wreg;
      t_wq   = pw + l * S_WQ;   pw += LL * S_WQ;
      t_wkv  = pw + l * S_WKV;  pw += LL * S_WKV;
      t_wo   = pw + l * S_WO;   pw += LL * S_WO;
      t_cwq  = pw + l * S_CWQ;  pw += LL * S_CWQ;
      t_cwkv = pw + l * S_CWKV; pw += LL * S_CWKV;
      t_cwo  = pw + l * S_CWO;  pw += LL * S_CWO;
      t_w1   = pw + l * S_W1;   pw += LL * S_W1;
      t_w2   = pw + l * S_W2;
    } else {
      u16* pw = wreg;
      t_wq = pw;   pw += S_WQ;
      t_wkv = pw;  pw += S_WKV;
      t_wo = pw;   pw += S_WO;
      t_cwq = pw;  pw += S_CWQ;
      t_cwkv = pw; pw += S_CWKV;
      t_cwo = pw;  pw += S_CWO;
      t_w1 = pw;   pw += S_W1;
      t_w2 = pw;
      wtrans_kernel<<<dim3(16, 16, 1), b256, 0, stream>>>(sa_wq  + (size_t)l * S_WQ,   sa_norm_g + l * 512, t_wq, 512, 512);
      wtrans_kernel<<<dim3(4, 16, 1),  b256, 0, stream>>>(sa_wkv + (size_t)l * S_WKV,  sa_norm_g + l * 512, t_wkv, 512, 128);
      wtrans_kernel<<<dim3(16, 16, 1), b256, 0, stream>>>(sa_wo  + (size_t)l * S_WO,   nullptr,             t_wo, 512, 512);
      wtrans_kernel<<<dim3(16, 16, 1), b256, 0, stream>>>(ca_wq  + (size_t)l * S_CWQ,  ca_norm_g + l * 512, t_cwq, 512, 512);
      wtrans_kernel<<<dim3(4, 8, 1),   b256, 0, stream>>>(ca_wkv + (size_t)l * S_CWKV, ca_ctx_g + l * 256,  t_cwkv, 256, 128);
      wtrans_kernel<<<dim3(16, 16, 1), b256, 0, stream>>>(ca_wo  + (size_t)l * S_CWO,  nullptr,             t_cwo, 512, 512);
      wtrans_kernel<<<dim3(128, 16, 1),b256, 0, stream>>>(ff_w1  + (size_t)l * S_W1,   ff_norm_g + l * 512, t_w1, 512, 4096);
      wtrans_kernel<<<dim3(16, 64, 1), b256, 0, stream>>>(ff_w2  + (size_t)l * S_W2,   nullptr,             t_w2, 2048, 512);
    }

    // ---- self attention ----
    ln_kernel<<<ROWS, b256, 0, stream>>>(x_cur, nullptr, nullptr, xn_bf, DD, 0, 1);
    mfma_gemm<128, 128, 0, 1><<<dim3(4, 32), b256, 0, stream>>>(xn_bf, t_wq, qlin, nullptr, 4096, 512, 512, qbf, 1);
    mfma_gemm<64, 64, 0, 0><<<dim3(2, 64), b256, 0, stream>>>(xn_bf, t_wkv, kvlin, nullptr, 4096, 128, 512, nullptr, 0);
    kvprep_kernel<<<BB * NKS_SA / 4, b256, 0, stream>>>(kvlin, l_sa_null, kbf, vtbf, 1025, NKS_SA, 1024, 1);
    attn_mfma_kernel<<<attn_grid, 128, 0, stream>>>(qbf, kbf, vtbf, bias_tab, big_bf, 1025, NKS_SA, 1, 1);
    mfma_gemm<128, 128, 0, 0><<<dim3(4, 32), b256, 0, stream>>>(big_bf, t_wo, qlin, nullptr, 4096, 512, 512, nullptr, 0);
    ln_fuse2_kernel<<<ROWS, b256, 0, stream>>>(qlin, l_sa_outg, x_cur, xn_bf);

    // ---- cross attention ----
    mfma_gemm<128, 128, 0, 1><<<dim3(4, 32), b256, 0, stream>>>(xn_bf, t_cwq, qlin, nullptr, 4096, 512, 512, qbf, 0);
    mfma_gemm<64, 64, 0, 0><<<dim3(2, 32), b256, 0, stream>>>(ctxn_bf, t_cwkv, kvlin, nullptr, 2048, 128, 256, nullptr, 0);
    kvprep_kernel<<<BB * NKS_CA / 4, b256, 0, stream>>>(kvlin, l_ca_null, kbf, vtbf, 513, NKS_CA, 512, 0);
    attn_mfma_kernel<<<attn_grid, 128, 0, stream>>>(qbf, kbf, vtbf, nullptr, big_bf, 513, NKS_CA, 0, 0);
    mfma_gemm<128, 128, 0, 0><<<dim3(4, 32), b256, 0, stream>>>(big_bf, t_cwo, qlin, nullptr, 4096, 512, 512, nullptr, 0);
    ln_fuse2_kernel<<<ROWS, b256, 0, stream>>>(qlin, l_ca_outg, x_cur, xn_bf);

    // ---- feed forward ----
    mfma_gemm_gated<<<dim3(32, 32), b256, 0, stream>>>(xn_bf, t_w1, ffh, 4096, 2048, 512);
    mfma_gemm<128, 128, 1, 0><<<dim3(4, 32), b256, 0, stream>>>(ffh, t_w2, x_cur, x_cur, 4096, 512, 2048, nullptr, 0);
  }

  // final stable layernorm, in-place into d_out
  ln_kernel<<<ROWS, b256, 0, stream>>>(x_cur, norm_g, nullptr, x_cur, DD, 1, 0);
}